// Round 14
// baseline (182.010 us; speedup 1.0000x reference)
//
#include <hip/hip_runtime.h>
#include <cmath>

#define N_NODES    100000
#define N_EDGES    1600000
#define NUM_GRAPHS 64

// counting-sort geometry
#define BUCK_W     512                               // nodes per coarse bucket
#define NBUCK      196                               // ceil(100000/512)
#define EPB        2048                              // edges per partition block
#define NB1        782                               // ceil(1600000/2048)
#define GEMM_GS    782                               // grid-stride blocks for gemm1/fused_mid
#define AGG_NPB    64                                // nodes per agg block (1563 blocks)

typedef __attribute__((ext_vector_type(8))) short bf16x8;
typedef __attribute__((ext_vector_type(4))) float f32x4;
typedef __attribute__((ext_vector_type(2))) float f32x2;

__device__ __forceinline__ ushort f2bf(float x) {
    union { float f; uint u; } v; v.f = x;
    uint r = v.u + 0x7fffu + ((v.u >> 16) & 1u);
    return (ushort)(r >> 16);
}
__device__ __forceinline__ float bf2f(ushort u) {
    union { uint u; float f; } v; v.u = ((uint)u) << 16;
    return v.f;
}
// f32 -> fp8 e4m3 (OCP) via HW converter, low byte
__device__ __forceinline__ unsigned char f2fp8(float v) {
    int p = __builtin_amdgcn_cvt_pk_fp8_f32(v, v, 0, false);
    return (unsigned char)(p & 0xFF);
}
// pack 8 f32 -> 8 fp8 (uint2)
__device__ __forceinline__ uint2 pack8_fp8(const float* r) {
    uint lo = (uint)__builtin_amdgcn_cvt_pk_fp8_f32(r[0], r[1], 0, false);
    lo = (uint)__builtin_amdgcn_cvt_pk_fp8_f32(r[2], r[3], (int)lo, true);
    uint hi = (uint)__builtin_amdgcn_cvt_pk_fp8_f32(r[4], r[5], 0, false);
    hi = (uint)__builtin_amdgcn_cvt_pk_fp8_f32(r[6], r[7], (int)hi, true);
    uint2 o; o.x = lo; o.y = hi; return o;
}
// accumulate 8 fp8 channels (one uint2) into f32 accumulators
__device__ __forceinline__ void accum8_fp8(float* a, uint2 V) {
    f32x2 d0 = __builtin_amdgcn_cvt_pk_f32_fp8((int)V.x, false);
    f32x2 d1 = __builtin_amdgcn_cvt_pk_f32_fp8((int)V.x, true);
    f32x2 d2 = __builtin_amdgcn_cvt_pk_f32_fp8((int)V.y, false);
    f32x2 d3 = __builtin_amdgcn_cvt_pk_f32_fp8((int)V.y, true);
    a[0] += d0.x; a[1] += d0.y; a[2] += d1.x; a[3] += d1.y;
    a[4] += d2.x; a[5] += d2.y; a[6] += d3.x; a[7] += d3.y;
}
// unpack 8 fp8 (uint2) -> bf16x8 fragment
__device__ __forceinline__ bf16x8 fp8_to_bf16x8(uint2 V) {
    f32x2 d0 = __builtin_amdgcn_cvt_pk_f32_fp8((int)V.x, false);
    f32x2 d1 = __builtin_amdgcn_cvt_pk_f32_fp8((int)V.x, true);
    f32x2 d2 = __builtin_amdgcn_cvt_pk_f32_fp8((int)V.y, false);
    f32x2 d3 = __builtin_amdgcn_cvt_pk_f32_fp8((int)V.y, true);
    bf16x8 t;
    t[0] = (short)f2bf(d0.x); t[1] = (short)f2bf(d0.y);
    t[2] = (short)f2bf(d1.x); t[3] = (short)f2bf(d1.y);
    t[4] = (short)f2bf(d2.x); t[5] = (short)f2bf(d2.y);
    t[6] = (short)f2bf(d3.x); t[7] = (short)f2bf(d3.y);
    return t;
}

// ========== K1: coarse histogram (blocks [0,NB1)) + gemm1 grid-stride (rest) ==========
// gemm1 emits y in fp8 e4m3 (the gathered representation, pre-activation).
__global__ __launch_bounds__(256) void k1_hist_gemm(
    const int* __restrict__ dst, int* __restrict__ bcount,
    const float* __restrict__ x, const float* __restrict__ W1,
    unsigned char* __restrict__ y8)
{
    if (blockIdx.x < NB1) {
        __shared__ int shist[NBUCK];
        int tid = threadIdx.x;
        for (int i = tid; i < NBUCK; i += 256) shist[i] = 0;
        __syncthreads();
        int e0 = blockIdx.x * EPB + tid;
        #pragma unroll
        for (int k = 0; k < EPB / 256; ++k) {
            int e = e0 + k * 256;
            if (e < N_EDGES) atomicAdd(&shist[dst[e] >> 9], 1);
        }
        __syncthreads();
        for (int i = tid; i < NBUCK; i += 256)
            bcount[blockIdx.x * NBUCK + i] = shist[i];
        return;
    }
    int bid = blockIdx.x - NB1;
    int lane = threadIdx.x & 63, wave = threadIdx.x >> 6;
    int lg = lane >> 4, lm = lane & 15;

    bf16x8 Bf[4][4];
    #pragma unroll
    for (int kc = 0; kc < 4; ++kc)
        #pragma unroll
        for (int cb = 0; cb < 4; ++cb) {
            bf16x8 t;
            #pragma unroll
            for (int i = 0; i < 8; ++i)
                t[i] = (short)f2bf(W1[(kc * 32 + lg * 8 + i) * 64 + cb * 16 + lm]);
            Bf[kc][cb] = t;
        }

    const int ntiles = N_NODES / 16;   // 6250
    for (int tile = bid * 4 + wave; tile < ntiles; tile += GEMM_GS * 4) {
        int r = tile * 16 + lm;
        f32x4 acc[4] = {};
        #pragma unroll
        for (int kc = 0; kc < 4; ++kc) {
            const float* p = x + (size_t)r * 128 + kc * 32 + lg * 8;
            float4 a0 = *(const float4*)p;
            float4 a1 = *(const float4*)(p + 4);
            bf16x8 af;
            af[0] = (short)f2bf(a0.x); af[1] = (short)f2bf(a0.y);
            af[2] = (short)f2bf(a0.z); af[3] = (short)f2bf(a0.w);
            af[4] = (short)f2bf(a1.x); af[5] = (short)f2bf(a1.y);
            af[6] = (short)f2bf(a1.z); af[7] = (short)f2bf(a1.w);
            #pragma unroll
            for (int cb = 0; cb < 4; ++cb)
                acc[cb] = __builtin_amdgcn_mfma_f32_16x16x32_bf16(af, Bf[kc][cb], acc[cb], 0, 0, 0);
        }
        #pragma unroll
        for (int cb = 0; cb < 4; ++cb)
            #pragma unroll
            for (int i = 0; i < 4; ++i)
                y8[(size_t)(tile * 16 + lg * 4 + i) * 64 + cb * 16 + lm] = f2fp8(acc[cb][i]);
    }
}

// ========== P2a: per-bucket exclusive scan over NB1 block counts (parallel) ==========
#define SCH 4   // 256*4 = 1024 >= NB1
__global__ __launch_bounds__(256) void p2a_scan(
    const int* __restrict__ bcount, int* __restrict__ basetab,
    int* __restrict__ btot)
{
    __shared__ int sh[256];
    int b = blockIdx.x, tid = threadIdx.x;
    int v[SCH];
    int tsum = 0;
    #pragma unroll
    for (int j = 0; j < SCH; ++j) {
        int blk = tid * SCH + j;
        v[j] = (blk < NB1) ? bcount[(size_t)blk * NBUCK + b] : 0;
        tsum += v[j];
    }
    sh[tid] = tsum;
    __syncthreads();
    for (int off = 1; off < 256; off <<= 1) {
        int t = (tid >= off) ? sh[tid - off] : 0;
        __syncthreads();
        sh[tid] += t;
        __syncthreads();
    }
    if (tid == 255) btot[b] = sh[255];
    int excl = sh[tid] - tsum;
    #pragma unroll
    for (int j = 0; j < SCH; ++j) {
        int blk = tid * SCH + j;
        if (blk < NB1) basetab[(size_t)b * NB1 + blk] = excl;
        excl += v[j];
    }
}

// ========== P2b: exclusive scan of bucket totals -> gbase ; zero pooled ==========
__global__ __launch_bounds__(256) void p2b_scan(
    const int* __restrict__ btot, int* __restrict__ gbase,
    float* __restrict__ pooled)
{
    int tid = threadIdx.x;
    for (int i = tid; i < NUM_GRAPHS * 128; i += 256) pooled[i] = 0.0f;
    __shared__ int v[NBUCK];
    for (int j = tid; j < NBUCK; j += 256) v[j] = btot[j];
    __syncthreads();
    if (tid == 0) {
        int run = 0;
        for (int j = 0; j < NBUCK; ++j) { int t = v[j]; v[j] = run; run += t; }
        gbase[NBUCK] = run;   // == N_EDGES
    }
    __syncthreads();
    for (int j = tid; j < NBUCK; j += 256) gbase[j] = v[j];
}

// ========== P3: partition edges into bucket-major packed array (simple LDS cursors) ==========
__global__ __launch_bounds__(256) void p3_partition(
    const int* __restrict__ src, const int* __restrict__ dst,
    const int* __restrict__ basetab, const int* __restrict__ gbase,
    uint* __restrict__ epack)
{
    __shared__ int cur[NBUCK];
    int blk = blockIdx.x, tid = threadIdx.x;
    for (int i = tid; i < NBUCK; i += 256)
        cur[i] = basetab[(size_t)i * NB1 + blk] + gbase[i];
    __syncthreads();
    int e0 = blk * EPB + tid;
    #pragma unroll
    for (int k = 0; k < EPB / 256; ++k) {
        int e = e0 + k * 256;
        if (e < N_EDGES) {
            int d = dst[e], s = src[e];
            int bin = d >> 9;
            int pos = atomicAdd(&cur[bin], 1);
            epack[pos] = ((uint)(d & 511) << 17) | (uint)s;
        }
    }
}

// ========== P4: per-bucket fine CSR (rowptr + esrc), all LDS ==========
__global__ __launch_bounds__(256) void p4_fine(
    const uint* __restrict__ epack, const int* __restrict__ gbase,
    int* __restrict__ rowptr, int* __restrict__ esrc)
{
    __shared__ int hist[BUCK_W];
    int b = blockIdx.x, tid = threadIdx.x;
    int beg = gbase[b], end = gbase[b + 1];
    for (int i = tid; i < BUCK_W; i += 256) hist[i] = 0;
    __syncthreads();
    for (int e = beg + tid; e < end; e += 256)
        atomicAdd(&hist[epack[e] >> 17], 1);
    __syncthreads();
    if (tid == 0) {
        int run = 0;
        for (int i = 0; i < BUCK_W; ++i) { int t = hist[i]; hist[i] = run; run += t; }
    }
    __syncthreads();
    for (int i = tid; i < BUCK_W; i += 256) {
        int n = b * BUCK_W + i;
        if (n < N_NODES) rowptr[n] = beg + hist[i];
    }
    if (b == NBUCK - 1 && tid == 0) rowptr[N_NODES] = end;
    __syncthreads();
    for (int e = beg + tid; e < end; e += 256) {
        uint v = epack[e];
        int slot = beg + atomicAdd(&hist[v >> 17], 1);
        esrc[slot] = (int)(v & 0x1FFFFu);
    }
}

// ====== gather fp8: 8-lane group per node, work-steal pool; emits relu(agg+bias) fp8 ======
__global__ __launch_bounds__(256) void agg_fp8(
    const uint2* __restrict__ in8, uint2* __restrict__ outact,
    const float* __restrict__ bias,
    const int* __restrict__ rowptr, const int* __restrict__ esrc)
{
    __shared__ int pool;
    if (threadIdx.x == 0) pool = 0;
    __syncthreads();

    int sub = threadIdx.x & 7;
    int wl  = threadIdx.x & 63;
    float bg[8];
    #pragma unroll
    for (int j = 0; j < 8; ++j) bg[j] = bias[sub * 8 + j];

    int base = blockIdx.x * AGG_NPB;
    int nmax = min(AGG_NPB, N_NODES - base);

    for (;;) {
        int n = 0;
        if (sub == 0) n = atomicAdd(&pool, 1);
        n = __shfl(n, wl & 56, 64);    // broadcast from group leader
        if (n >= nmax) break;
        int node = base + n;

        float a[8] = {0, 0, 0, 0, 0, 0, 0, 0};
        accum8_fp8(a, in8[(size_t)node * 8 + sub]);   // self term

        int e = rowptr[node], end = rowptr[node + 1];
        for (; e + 8 <= end; e += 8) {
            int i0 = esrc[e],     i1 = esrc[e + 1], i2 = esrc[e + 2], i3 = esrc[e + 3];
            int i4 = esrc[e + 4], i5 = esrc[e + 5], i6 = esrc[e + 6], i7 = esrc[e + 7];
            uint2 v0 = in8[(size_t)i0 * 8 + sub];
            uint2 v1 = in8[(size_t)i1 * 8 + sub];
            uint2 v2 = in8[(size_t)i2 * 8 + sub];
            uint2 v3 = in8[(size_t)i3 * 8 + sub];
            uint2 v4 = in8[(size_t)i4 * 8 + sub];
            uint2 v5 = in8[(size_t)i5 * 8 + sub];
            uint2 v6 = in8[(size_t)i6 * 8 + sub];
            uint2 v7 = in8[(size_t)i7 * 8 + sub];
            accum8_fp8(a, v0); accum8_fp8(a, v1); accum8_fp8(a, v2); accum8_fp8(a, v3);
            accum8_fp8(a, v4); accum8_fp8(a, v5); accum8_fp8(a, v6); accum8_fp8(a, v7);
        }
        if (e + 4 <= end) {
            int i0 = esrc[e], i1 = esrc[e + 1], i2 = esrc[e + 2], i3 = esrc[e + 3];
            uint2 v0 = in8[(size_t)i0 * 8 + sub];
            uint2 v1 = in8[(size_t)i1 * 8 + sub];
            uint2 v2 = in8[(size_t)i2 * 8 + sub];
            uint2 v3 = in8[(size_t)i3 * 8 + sub];
            accum8_fp8(a, v0); accum8_fp8(a, v1); accum8_fp8(a, v2); accum8_fp8(a, v3);
            e += 4;
        }
        for (; e < end; ++e)
            accum8_fp8(a, in8[(size_t)esrc[e] * 8 + sub]);

        float r[8];
        #pragma unroll
        for (int j = 0; j < 8; ++j) r[j] = fmaxf(a[j] + bg[j], 0.0f);
        outact[(size_t)node * 8 + sub] = pack8_fp8(r);
    }
}

// ===== fused_mid: h1=relu(t@W2+b2); z=h1@W3 ; t = fp8 post-act input =====
__global__ __launch_bounds__(256) void fused_mid(
    const uint2* __restrict__ yact, const float* __restrict__ W2,
    const float* __restrict__ b2, const float* __restrict__ W3,
    unsigned char* __restrict__ z8)
{
    __shared__ __align__(16) float trs[4][16 * 68];
    int lane = threadIdx.x & 63, wave = threadIdx.x >> 6;
    int lg = lane >> 4, lm = lane & 15;

    bf16x8 B2[2][4], B3[2][4];
    #pragma unroll
    for (int kc = 0; kc < 2; ++kc)
        #pragma unroll
        for (int cb = 0; cb < 4; ++cb) {
            bf16x8 t2, t3;
            #pragma unroll
            for (int i = 0; i < 8; ++i) {
                int k = kc * 32 + lg * 8 + i;
                int cc = cb * 16 + lm;
                t2[i] = (short)f2bf(W2[k * 64 + cc]);
                t3[i] = (short)f2bf(W3[k * 64 + cc]);
            }
            B2[kc][cb] = t2; B3[kc][cb] = t3;
        }
    float b2r[4];
    #pragma unroll
    for (int cb = 0; cb < 4; ++cb) b2r[cb] = b2[cb * 16 + lm];

    const int ntiles = N_NODES / 16;
    for (int tile = blockIdx.x * 4 + wave; tile < ntiles; tile += GEMM_GS * 4) {
        int r = tile * 16 + lm;
        bf16x8 A1[2];
        #pragma unroll
        for (int kc = 0; kc < 2; ++kc)
            A1[kc] = fp8_to_bf16x8(yact[(size_t)r * 8 + kc * 4 + lg]);
        f32x4 acc[4] = {};
        #pragma unroll
        for (int kc = 0; kc < 2; ++kc)
            #pragma unroll
            for (int cb = 0; cb < 4; ++cb)
                acc[cb] = __builtin_amdgcn_mfma_f32_16x16x32_bf16(A1[kc], B2[kc][cb], acc[cb], 0, 0, 0);
        #pragma unroll
        for (int cb = 0; cb < 4; ++cb)
            #pragma unroll
            for (int i = 0; i < 4; ++i)
                trs[wave][(lg * 4 + i) * 68 + cb * 16 + lm] = fmaxf(acc[cb][i] + b2r[cb], 0.0f);
        bf16x8 A2[2];
        #pragma unroll
        for (int kc = 0; kc < 2; ++kc) {
            const float* p = &trs[wave][lm * 68 + kc * 32 + lg * 8];
            float4 u0 = *(const float4*)p;
            float4 u1 = *(const float4*)(p + 4);
            bf16x8 t;
            t[0] = (short)f2bf(u0.x); t[1] = (short)f2bf(u0.y);
            t[2] = (short)f2bf(u0.z); t[3] = (short)f2bf(u0.w);
            t[4] = (short)f2bf(u1.x); t[5] = (short)f2bf(u1.y);
            t[6] = (short)f2bf(u1.z); t[7] = (short)f2bf(u1.w);
            A2[kc] = t;
        }
        f32x4 acc2[4] = {};
        #pragma unroll
        for (int kc = 0; kc < 2; ++kc)
            #pragma unroll
            for (int cb = 0; cb < 4; ++cb)
                acc2[cb] = __builtin_amdgcn_mfma_f32_16x16x32_bf16(A2[kc], B3[kc][cb], acc2[cb], 0, 0, 0);
        #pragma unroll
        for (int cb = 0; cb < 4; ++cb)
            #pragma unroll
            for (int i = 0; i < 4; ++i)
                z8[(size_t)(tile * 16 + lg * 4 + i) * 64 + cb * 16 + lm] = f2fp8(acc2[cb][i]);
    }
}

// ===== k4 MFMA: o = t@W4+b4 (t = fp8 post-act) ; pooled[batch[r]] += o =====
__global__ __launch_bounds__(256) void k4_mfma_pool(
    const uint2* __restrict__ zact, const float* __restrict__ W4,
    const float* __restrict__ b4, const int* __restrict__ batch,
    float* __restrict__ pooled)
{
    int lane = threadIdx.x & 63, wave = threadIdx.x >> 6;
    int lg = lane >> 4, lm = lane & 15;

    bf16x8 B4[2][8];
    #pragma unroll
    for (int kc = 0; kc < 2; ++kc)
        #pragma unroll
        for (int cb = 0; cb < 8; ++cb) {
            bf16x8 t;
            #pragma unroll
            for (int i = 0; i < 8; ++i)
                t[i] = (short)f2bf(W4[(kc * 32 + lg * 8 + i) * 128 + cb * 16 + lm]);
            B4[kc][cb] = t;
        }
    float b4r[8];
    #pragma unroll
    for (int cb = 0; cb < 8; ++cb) b4r[cb] = b4[cb * 16 + lm];

    const int NT = N_NODES / 16;   // 6250
    const int TPW = 4;
    int w = blockIdx.x * 4 + wave;
    int t0 = w * TPW;
    if (t0 >= NT) return;
    int t1 = min(t0 + TPW, NT);

    float pacc[8] = {0, 0, 0, 0, 0, 0, 0, 0};
    int curg = batch[t0 * 16];

#define FLUSH(G) do {                                                     \
        _Pragma("unroll")                                                 \
        for (int cb = 0; cb < 8; ++cb) {                                  \
            float v = pacc[cb];                                           \
            v += __shfl_xor(v, 16, 64);                                   \
            v += __shfl_xor(v, 32, 64);                                   \
            if (lane < 16) unsafeAtomicAdd(&pooled[(G) * 128 + cb * 16 + lm], v); \
            pacc[cb] = 0.0f;                                              \
        }                                                                 \
    } while (0)

    for (int t = t0; t < t1; ++t) {
        int rbase = t * 16;
        int r = rbase + lm;
        bf16x8 A[2];
        #pragma unroll
        for (int kc = 0; kc < 2; ++kc)
            A[kc] = fp8_to_bf16x8(zact[(size_t)r * 8 + kc * 4 + lg]);
        f32x4 acc[8] = {};
        #pragma unroll
        for (int kc = 0; kc < 2; ++kc)
            #pragma unroll
            for (int cb = 0; cb < 8; ++cb)
                acc[cb] = __builtin_amdgcn_mfma_f32_16x16x32_bf16(A[kc], B4[kc][cb], acc[cb], 0, 0, 0);

        int g0 = batch[rbase], g15 = batch[rbase + 15];
        if (g0 != curg) { FLUSH(curg); curg = g0; }
        if (g0 == g15) {
            #pragma unroll
            for (int cb = 0; cb < 8; ++cb)
                pacc[cb] += acc[cb][0] + acc[cb][1] + acc[cb][2] + acc[cb][3]
                            + 4.0f * b4r[cb];
        } else {
            FLUSH(curg);
            #pragma unroll
            for (int i = 0; i < 4; ++i) {
                int gi = batch[rbase + lg * 4 + i];
                #pragma unroll
                for (int cb = 0; cb < 8; ++cb)
                    unsafeAtomicAdd(&pooled[gi * 128 + cb * 16 + lm],
                                    acc[cb][i] + b4r[cb]);
            }
            curg = g15;
        }
    }
    FLUSH(curg);
#undef FLUSH
}

// ================= head =================
__global__ void head_kernel(
    const float* __restrict__ pooled, const int* __restrict__ batch,
    const float* __restrict__ Wfc, const float* __restrict__ bfc,
    float* __restrict__ out)
{
    int g = threadIdx.x;
    if (g >= NUM_GRAPHS) return;

    int lo = 0, hi = N_NODES;
    while (lo < hi) { int mid = (lo + hi) >> 1; if (batch[mid] < g) lo = mid + 1; else hi = mid; }
    int beg = lo;
    lo = 0; hi = N_NODES;
    while (lo < hi) { int mid = (lo + hi) >> 1; if (batch[mid] < g + 1) lo = mid + 1; else hi = mid; }
    int cnt = lo - beg;
    float inv = 1.0f / fmaxf((float)cnt, 1.0f);

    float logits[10];
    for (int o = 0; o < 10; ++o) {
        float acc = 0.0f;
        for (int k = 0; k < 128; ++k)
            acc = fmaf(pooled[g * 128 + k], Wfc[k * 10 + o], acc);
        logits[o] = acc * inv + bfc[o];
    }
    float m = -INFINITY;
    for (int o = 0; o < 10; ++o) m = fmaxf(m, logits[o]);
    float s = 0.0f;
    for (int o = 0; o < 10; ++o) s += expf(logits[o] - m);
    float ls = logf(s);
    for (int o = 0; o < 10; ++o) out[g * 10 + o] = logits[o] - m - ls;
}

extern "C" void kernel_launch(void* const* d_in, const int* in_sizes, int n_in,
                              void* d_out, int out_size, void* d_ws, size_t ws_size,
                              hipStream_t stream)
{
    const float* x     = (const float*)d_in[0];
    const int*   ei    = (const int*)d_in[1];
    const int*   src   = ei;
    const int*   dst   = ei + N_EDGES;
    const int*   batch = (const int*)d_in[2];
    const float* W1  = (const float*)d_in[3];
    const float* b1  = (const float*)d_in[4];
    const float* W2  = (const float*)d_in[5];
    const float* b2  = (const float*)d_in[6];
    const float* W3  = (const float*)d_in[7];
    const float* b3  = (const float*)d_in[8];
    const float* W4  = (const float*)d_in[9];
    const float* b4  = (const float*)d_in[10];
    const float* Wfc = (const float*)d_in[11];
    const float* bfc = (const float*)d_in[12];
    float* out = (float*)d_out;

    char* ws = (char*)d_ws;
    unsigned char* yfp8 = (unsigned char*)(ws);              // 6.4 MB (fp8 y, pre-act)
    unsigned char* zfp8 = (unsigned char*)(ws + 6400000);    // 6.4 MB (fp8 z, pre-act)
    uint2* yact  = (uint2*)(ws + 12800000);                  // 6.4 MB (fp8 relu(yagg+b1))
    uint2* zact  = (uint2*)(ws + 19200000);                  // 6.4 MB (fp8 relu(zagg+b3))
    int*  esrc    = (int*) (ws + 25600000);                  // 6.4 MB
    uint* epack   = (uint*)(ws + 32000000);                  // 6.4 MB
    int*  rowptr  = (int*) (ws + 38400000);                  // 400,004 B
    int*  bcount  = (int*) (ws + 38800016);                  // 613,088 B
    int*  basetab = (int*) (ws + 39413104);                  // 613,088 B
    int*  btot    = (int*) (ws + 40026192);                  // 784 B
    int*  gbase   = (int*) (ws + 40026976);                  // 788 B
    float* pooled = (float*)(ws + 40027776);                 // 32 KB

    // ---- K1: coarse hist + gemm1 (fp8 out) ----
    k1_hist_gemm<<<NB1 + GEMM_GS, 256, 0, stream>>>(dst, bcount, x, W1, yfp8);
    // ---- CSR build ----
    p2a_scan<<<NBUCK, 256, 0, stream>>>(bcount, basetab, btot);
    p2b_scan<<<1, 256, 0, stream>>>(btot, gbase, pooled);
    p3_partition<<<NB1, 256, 0, stream>>>(src, dst, basetab, gbase, epack);
    p4_fine<<<NBUCK, 256, 0, stream>>>(epack, gbase, rowptr, esrc);

    // ---- layer 1 ----
    agg_fp8<<<(N_NODES + AGG_NPB - 1) / AGG_NPB, 256, 0, stream>>>(
        (const uint2*)yfp8, yact, b1, rowptr, esrc);
    fused_mid<<<GEMM_GS, 256, 0, stream>>>(yact, W2, b2, W3, zfp8);

    // ---- layer 2 ----
    agg_fp8<<<(N_NODES + AGG_NPB - 1) / AGG_NPB, 256, 0, stream>>>(
        (const uint2*)zfp8, zact, b3, rowptr, esrc);
    {
        const int NT = N_NODES / 16;   // 6250
        const int TPW = 4;
        int blocks = (NT + 4 * TPW - 1) / (4 * TPW);   // 391
        k4_mfma_pool<<<blocks, 256, 0, stream>>>(zact, W4, b4, batch, pooled);
    }

    head_kernel<<<1, 64, 0, stream>>>(pooled, batch, Wfc, bfc, out);
}

// Round 15
// 173.559 us; speedup vs baseline: 1.0487x; 1.0487x over previous
//
#include <hip/hip_runtime.h>
#include <cmath>

#define N_NODES    100000
#define N_EDGES    1600000
#define NUM_GRAPHS 64

// counting-sort geometry
#define BUCK_W     512                               // nodes per coarse bucket
#define NBUCK      196                               // ceil(100000/512)
#define EPB        2048                              // edges per partition block
#define NB1        782                               // ceil(1600000/2048)
#define GEMM_GS    782                               // grid-stride blocks for gemm1/fused_mid
#define AGG_NPB    64                                // nodes per agg block (1563 blocks)

typedef __attribute__((ext_vector_type(8))) short bf16x8;
typedef __attribute__((ext_vector_type(4))) float f32x4;
typedef __attribute__((ext_vector_type(2))) float f32x2;

__device__ __forceinline__ ushort f2bf(float x) {
    union { float f; uint u; } v; v.f = x;
    uint r = v.u + 0x7fffu + ((v.u >> 16) & 1u);
    return (ushort)(r >> 16);
}
__device__ __forceinline__ float bf2f(ushort u) {
    union { uint u; float f; } v; v.u = ((uint)u) << 16;
    return v.f;
}
// f32 -> fp8 e4m3 (OCP) via HW converter, low byte
__device__ __forceinline__ unsigned char f2fp8(float v) {
    int p = __builtin_amdgcn_cvt_pk_fp8_f32(v, v, 0, false);
    return (unsigned char)(p & 0xFF);
}
// accumulate 8 fp8 channels (one uint2) into f32 accumulators
__device__ __forceinline__ void accum8_fp8(float* a, uint2 V) {
    f32x2 d0 = __builtin_amdgcn_cvt_pk_f32_fp8((int)V.x, false);
    f32x2 d1 = __builtin_amdgcn_cvt_pk_f32_fp8((int)V.x, true);
    f32x2 d2 = __builtin_amdgcn_cvt_pk_f32_fp8((int)V.y, false);
    f32x2 d3 = __builtin_amdgcn_cvt_pk_f32_fp8((int)V.y, true);
    a[0] += d0.x; a[1] += d0.y; a[2] += d1.x; a[3] += d1.y;
    a[4] += d2.x; a[5] += d2.y; a[6] += d3.x; a[7] += d3.y;
}

// ========== K1: coarse histogram (blocks [0,NB1)) + gemm1 grid-stride (rest) ==========
// gemm1 emits y in fp8 e4m3 (the gathered representation, pre-activation).
__global__ __launch_bounds__(256) void k1_hist_gemm(
    const int* __restrict__ dst, int* __restrict__ bcount,
    const float* __restrict__ x, const float* __restrict__ W1,
    unsigned char* __restrict__ y8)
{
    if (blockIdx.x < NB1) {
        __shared__ int shist[NBUCK];
        int tid = threadIdx.x;
        for (int i = tid; i < NBUCK; i += 256) shist[i] = 0;
        __syncthreads();
        int e0 = blockIdx.x * EPB + tid;
        #pragma unroll
        for (int k = 0; k < EPB / 256; ++k) {
            int e = e0 + k * 256;
            if (e < N_EDGES) atomicAdd(&shist[dst[e] >> 9], 1);
        }
        __syncthreads();
        for (int i = tid; i < NBUCK; i += 256)
            bcount[blockIdx.x * NBUCK + i] = shist[i];
        return;
    }
    int bid = blockIdx.x - NB1;
    int lane = threadIdx.x & 63, wave = threadIdx.x >> 6;
    int lg = lane >> 4, lm = lane & 15;

    bf16x8 Bf[4][4];
    #pragma unroll
    for (int kc = 0; kc < 4; ++kc)
        #pragma unroll
        for (int cb = 0; cb < 4; ++cb) {
            bf16x8 t;
            #pragma unroll
            for (int i = 0; i < 8; ++i)
                t[i] = (short)f2bf(W1[(kc * 32 + lg * 8 + i) * 64 + cb * 16 + lm]);
            Bf[kc][cb] = t;
        }

    const int ntiles = N_NODES / 16;   // 6250
    for (int tile = bid * 4 + wave; tile < ntiles; tile += GEMM_GS * 4) {
        int r = tile * 16 + lm;
        f32x4 acc[4] = {};
        #pragma unroll
        for (int kc = 0; kc < 4; ++kc) {
            const float* p = x + (size_t)r * 128 + kc * 32 + lg * 8;
            float4 a0 = *(const float4*)p;
            float4 a1 = *(const float4*)(p + 4);
            bf16x8 af;
            af[0] = (short)f2bf(a0.x); af[1] = (short)f2bf(a0.y);
            af[2] = (short)f2bf(a0.z); af[3] = (short)f2bf(a0.w);
            af[4] = (short)f2bf(a1.x); af[5] = (short)f2bf(a1.y);
            af[6] = (short)f2bf(a1.z); af[7] = (short)f2bf(a1.w);
            #pragma unroll
            for (int cb = 0; cb < 4; ++cb)
                acc[cb] = __builtin_amdgcn_mfma_f32_16x16x32_bf16(af, Bf[kc][cb], acc[cb], 0, 0, 0);
        }
        #pragma unroll
        for (int cb = 0; cb < 4; ++cb)
            #pragma unroll
            for (int i = 0; i < 4; ++i)
                y8[(size_t)(tile * 16 + lg * 4 + i) * 64 + cb * 16 + lm] = f2fp8(acc[cb][i]);
    }
}

// ========== P2a: per-bucket exclusive scan over NB1 block counts (parallel) ==========
#define SCH 4   // 256*4 = 1024 >= NB1
__global__ __launch_bounds__(256) void p2a_scan(
    const int* __restrict__ bcount, int* __restrict__ basetab,
    int* __restrict__ btot)
{
    __shared__ int sh[256];
    int b = blockIdx.x, tid = threadIdx.x;
    int v[SCH];
    int tsum = 0;
    #pragma unroll
    for (int j = 0; j < SCH; ++j) {
        int blk = tid * SCH + j;
        v[j] = (blk < NB1) ? bcount[(size_t)blk * NBUCK + b] : 0;
        tsum += v[j];
    }
    sh[tid] = tsum;
    __syncthreads();
    for (int off = 1; off < 256; off <<= 1) {
        int t = (tid >= off) ? sh[tid - off] : 0;
        __syncthreads();
        sh[tid] += t;
        __syncthreads();
    }
    if (tid == 255) btot[b] = sh[255];
    int excl = sh[tid] - tsum;
    #pragma unroll
    for (int j = 0; j < SCH; ++j) {
        int blk = tid * SCH + j;
        if (blk < NB1) basetab[(size_t)b * NB1 + blk] = excl;
        excl += v[j];
    }
}

// ========== P2b: exclusive scan of bucket totals -> gbase ; zero pooled ==========
__global__ __launch_bounds__(256) void p2b_scan(
    const int* __restrict__ btot, int* __restrict__ gbase,
    float* __restrict__ pooled)
{
    int tid = threadIdx.x;
    for (int i = tid; i < NUM_GRAPHS * 128; i += 256) pooled[i] = 0.0f;
    __shared__ int v[NBUCK];
    for (int j = tid; j < NBUCK; j += 256) v[j] = btot[j];
    __syncthreads();
    if (tid == 0) {
        int run = 0;
        for (int j = 0; j < NBUCK; ++j) { int t = v[j]; v[j] = run; run += t; }
        gbase[NBUCK] = run;   // == N_EDGES
    }
    __syncthreads();
    for (int j = tid; j < NBUCK; j += 256) gbase[j] = v[j];
}

// ========== P3: partition edges into bucket-major packed array ==========
__global__ __launch_bounds__(256) void p3_partition(
    const int* __restrict__ src, const int* __restrict__ dst,
    const int* __restrict__ basetab, const int* __restrict__ gbase,
    uint* __restrict__ epack)
{
    __shared__ int cur[NBUCK];
    int blk = blockIdx.x, tid = threadIdx.x;
    for (int i = tid; i < NBUCK; i += 256)
        cur[i] = basetab[(size_t)i * NB1 + blk] + gbase[i];
    __syncthreads();
    int e0 = blk * EPB + tid;
    #pragma unroll
    for (int k = 0; k < EPB / 256; ++k) {
        int e = e0 + k * 256;
        if (e < N_EDGES) {
            int d = dst[e], s = src[e];
            int bin = d >> 9;
            int pos = atomicAdd(&cur[bin], 1);
            epack[pos] = ((uint)(d & 511) << 17) | (uint)s;
        }
    }
}

// ========== P4: per-bucket fine CSR (rowptr + esrc), all LDS ==========
__global__ __launch_bounds__(256) void p4_fine(
    const uint* __restrict__ epack, const int* __restrict__ gbase,
    int* __restrict__ rowptr, int* __restrict__ esrc)
{
    __shared__ int hist[BUCK_W];
    int b = blockIdx.x, tid = threadIdx.x;
    int beg = gbase[b], end = gbase[b + 1];
    for (int i = tid; i < BUCK_W; i += 256) hist[i] = 0;
    __syncthreads();
    for (int e = beg + tid; e < end; e += 256)
        atomicAdd(&hist[epack[e] >> 17], 1);
    __syncthreads();
    if (tid == 0) {
        int run = 0;
        for (int i = 0; i < BUCK_W; ++i) { int t = hist[i]; hist[i] = run; run += t; }
    }
    __syncthreads();
    for (int i = tid; i < BUCK_W; i += 256) {
        int n = b * BUCK_W + i;
        if (n < N_NODES) rowptr[n] = beg + hist[i];
    }
    if (b == NBUCK - 1 && tid == 0) rowptr[N_NODES] = end;
    __syncthreads();
    for (int e = beg + tid; e < end; e += 256) {
        uint v = epack[e];
        int slot = beg + atomicAdd(&hist[v >> 17], 1);
        esrc[slot] = (int)(v & 0x1FFFFu);
    }
}

// ====== gather fp8 (v4 structure): 8-lane group per node, work-steal pool ======
// Input rows are 64 ch fp8 = 64 B; each lane loads uint2 (8 ch), f32-accumulates,
// output written as bf16 (128 B rows) for the MFMA consumers.
__global__ __launch_bounds__(256) void agg_fp8(
    const uint2* __restrict__ in8, uint4* __restrict__ out4,
    const int* __restrict__ rowptr, const int* __restrict__ esrc)
{
    __shared__ int pool;
    if (threadIdx.x == 0) pool = 0;
    __syncthreads();

    int sub = threadIdx.x & 7;
    int wl  = threadIdx.x & 63;
    int base = blockIdx.x * AGG_NPB;
    int nmax = min(AGG_NPB, N_NODES - base);

    for (;;) {
        int n = 0;
        if (sub == 0) n = atomicAdd(&pool, 1);
        n = __shfl(n, wl & 56, 64);    // broadcast from group leader
        if (n >= nmax) break;
        int node = base + n;

        float a[8] = {0, 0, 0, 0, 0, 0, 0, 0};
        accum8_fp8(a, in8[(size_t)node * 8 + sub]);   // self term

        int e = rowptr[node], end = rowptr[node + 1];
        for (; e + 8 <= end; e += 8) {
            int i0 = esrc[e],     i1 = esrc[e + 1], i2 = esrc[e + 2], i3 = esrc[e + 3];
            int i4 = esrc[e + 4], i5 = esrc[e + 5], i6 = esrc[e + 6], i7 = esrc[e + 7];
            uint2 v0 = in8[(size_t)i0 * 8 + sub];
            uint2 v1 = in8[(size_t)i1 * 8 + sub];
            uint2 v2 = in8[(size_t)i2 * 8 + sub];
            uint2 v3 = in8[(size_t)i3 * 8 + sub];
            uint2 v4 = in8[(size_t)i4 * 8 + sub];
            uint2 v5 = in8[(size_t)i5 * 8 + sub];
            uint2 v6 = in8[(size_t)i6 * 8 + sub];
            uint2 v7 = in8[(size_t)i7 * 8 + sub];
            accum8_fp8(a, v0); accum8_fp8(a, v1); accum8_fp8(a, v2); accum8_fp8(a, v3);
            accum8_fp8(a, v4); accum8_fp8(a, v5); accum8_fp8(a, v6); accum8_fp8(a, v7);
        }
        if (e + 4 <= end) {
            int i0 = esrc[e], i1 = esrc[e + 1], i2 = esrc[e + 2], i3 = esrc[e + 3];
            uint2 v0 = in8[(size_t)i0 * 8 + sub];
            uint2 v1 = in8[(size_t)i1 * 8 + sub];
            uint2 v2 = in8[(size_t)i2 * 8 + sub];
            uint2 v3 = in8[(size_t)i3 * 8 + sub];
            accum8_fp8(a, v0); accum8_fp8(a, v1); accum8_fp8(a, v2); accum8_fp8(a, v3);
            e += 4;
        }
        for (; e < end; ++e)
            accum8_fp8(a, in8[(size_t)esrc[e] * 8 + sub]);

        uint4 o;
        o.x = (uint)f2bf(a[0]) | ((uint)f2bf(a[1]) << 16);
        o.y = (uint)f2bf(a[2]) | ((uint)f2bf(a[3]) << 16);
        o.z = (uint)f2bf(a[4]) | ((uint)f2bf(a[5]) << 16);
        o.w = (uint)f2bf(a[6]) | ((uint)f2bf(a[7]) << 16);
        out4[(size_t)node * 8 + sub] = o;
    }
}

// ===== fused_mid: t=relu(yagg+b1); h1=relu(t@W2+b2); z=h1@W3 (bf16 MFMA, fp8 out) =====
__global__ __launch_bounds__(256) void fused_mid(
    const ushort* __restrict__ yagg, const float* __restrict__ b1,
    const float* __restrict__ W2, const float* __restrict__ b2,
    const float* __restrict__ W3, unsigned char* __restrict__ z8)
{
    __shared__ __align__(16) float trs[4][16 * 68];
    int lane = threadIdx.x & 63, wave = threadIdx.x >> 6;
    int lg = lane >> 4, lm = lane & 15;

    bf16x8 B2[2][4], B3[2][4];
    #pragma unroll
    for (int kc = 0; kc < 2; ++kc)
        #pragma unroll
        for (int cb = 0; cb < 4; ++cb) {
            bf16x8 t2, t3;
            #pragma unroll
            for (int i = 0; i < 8; ++i) {
                int k = kc * 32 + lg * 8 + i;
                int cc = cb * 16 + lm;
                t2[i] = (short)f2bf(W2[k * 64 + cc]);
                t3[i] = (short)f2bf(W3[k * 64 + cc]);
            }
            B2[kc][cb] = t2; B3[kc][cb] = t3;
        }
    float b1r[2][8];
    #pragma unroll
    for (int kc = 0; kc < 2; ++kc)
        #pragma unroll
        for (int i = 0; i < 8; ++i)
            b1r[kc][i] = b1[kc * 32 + lg * 8 + i];
    float b2r[4];
    #pragma unroll
    for (int cb = 0; cb < 4; ++cb) b2r[cb] = b2[cb * 16 + lm];

    const int ntiles = N_NODES / 16;
    for (int tile = blockIdx.x * 4 + wave; tile < ntiles; tile += GEMM_GS * 4) {
        int r = tile * 16 + lm;
        bf16x8 A1[2];
        #pragma unroll
        for (int kc = 0; kc < 2; ++kc) {
            uint4 raw = *(const uint4*)(yagg + (size_t)r * 64 + kc * 32 + lg * 8);
            uint w[4] = {raw.x, raw.y, raw.z, raw.w};
            bf16x8 t;
            #pragma unroll
            for (int j = 0; j < 4; ++j) {
                float flo = bf2f((ushort)(w[j] & 0xffffu)) + b1r[kc][2 * j];
                float fhi = bf2f((ushort)(w[j] >> 16)) + b1r[kc][2 * j + 1];
                t[2 * j]     = (short)f2bf(fmaxf(flo, 0.0f));
                t[2 * j + 1] = (short)f2bf(fmaxf(fhi, 0.0f));
            }
            A1[kc] = t;
        }
        f32x4 acc[4] = {};
        #pragma unroll
        for (int kc = 0; kc < 2; ++kc)
            #pragma unroll
            for (int cb = 0; cb < 4; ++cb)
                acc[cb] = __builtin_amdgcn_mfma_f32_16x16x32_bf16(A1[kc], B2[kc][cb], acc[cb], 0, 0, 0);
        #pragma unroll
        for (int cb = 0; cb < 4; ++cb)
            #pragma unroll
            for (int i = 0; i < 4; ++i)
                trs[wave][(lg * 4 + i) * 68 + cb * 16 + lm] = fmaxf(acc[cb][i] + b2r[cb], 0.0f);
        bf16x8 A2[2];
        #pragma unroll
        for (int kc = 0; kc < 2; ++kc) {
            const float* p = &trs[wave][lm * 68 + kc * 32 + lg * 8];
            float4 u0 = *(const float4*)p;
            float4 u1 = *(const float4*)(p + 4);
            bf16x8 t;
            t[0] = (short)f2bf(u0.x); t[1] = (short)f2bf(u0.y);
            t[2] = (short)f2bf(u0.z); t[3] = (short)f2bf(u0.w);
            t[4] = (short)f2bf(u1.x); t[5] = (short)f2bf(u1.y);
            t[6] = (short)f2bf(u1.z); t[7] = (short)f2bf(u1.w);
            A2[kc] = t;
        }
        f32x4 acc2[4] = {};
        #pragma unroll
        for (int kc = 0; kc < 2; ++kc)
            #pragma unroll
            for (int cb = 0; cb < 4; ++cb)
                acc2[cb] = __builtin_amdgcn_mfma_f32_16x16x32_bf16(A2[kc], B3[kc][cb], acc2[cb], 0, 0, 0);
        #pragma unroll
        for (int cb = 0; cb < 4; ++cb)
            #pragma unroll
            for (int i = 0; i < 4; ++i)
                z8[(size_t)(tile * 16 + lg * 4 + i) * 64 + cb * 16 + lm] = f2fp8(acc2[cb][i]);
    }
}

// ===== k4 MFMA: o = relu(zagg+b3)@W4+b4 ; pooled[batch[r]] += o =====
__global__ __launch_bounds__(256) void k4_mfma_pool(
    const ushort* __restrict__ zagg, const float* __restrict__ b3,
    const float* __restrict__ W4, const float* __restrict__ b4,
    const int* __restrict__ batch, float* __restrict__ pooled)
{
    int lane = threadIdx.x & 63, wave = threadIdx.x >> 6;
    int lg = lane >> 4, lm = lane & 15;

    bf16x8 B4[2][8];
    #pragma unroll
    for (int kc = 0; kc < 2; ++kc)
        #pragma unroll
        for (int cb = 0; cb < 8; ++cb) {
            bf16x8 t;
            #pragma unroll
            for (int i = 0; i < 8; ++i)
                t[i] = (short)f2bf(W4[(kc * 32 + lg * 8 + i) * 128 + cb * 16 + lm]);
            B4[kc][cb] = t;
        }
    float b3r[2][8];
    #pragma unroll
    for (int kc = 0; kc < 2; ++kc)
        #pragma unroll
        for (int i = 0; i < 8; ++i)
            b3r[kc][i] = b3[kc * 32 + lg * 8 + i];
    float b4r[8];
    #pragma unroll
    for (int cb = 0; cb < 8; ++cb) b4r[cb] = b4[cb * 16 + lm];

    const int NT = N_NODES / 16;   // 6250
    const int TPW = 4;
    int w = blockIdx.x * 4 + wave;
    int t0 = w * TPW;
    if (t0 >= NT) return;
    int t1 = min(t0 + TPW, NT);

    float pacc[8] = {0, 0, 0, 0, 0, 0, 0, 0};
    int curg = batch[t0 * 16];

#define FLUSH(G) do {                                                     \
        _Pragma("unroll")                                                 \
        for (int cb = 0; cb < 8; ++cb) {                                  \
            float v = pacc[cb];                                           \
            v += __shfl_xor(v, 16, 64);                                   \
            v += __shfl_xor(v, 32, 64);                                   \
            if (lane < 16) unsafeAtomicAdd(&pooled[(G) * 128 + cb * 16 + lm], v); \
            pacc[cb] = 0.0f;                                              \
        }                                                                 \
    } while (0)

    for (int t = t0; t < t1; ++t) {
        int rbase = t * 16;
        int r = rbase + lm;
        bf16x8 A[2];
        #pragma unroll
        for (int kc = 0; kc < 2; ++kc) {
            uint4 raw = *(const uint4*)(zagg + (size_t)r * 64 + kc * 32 + lg * 8);
            uint wv[4] = {raw.x, raw.y, raw.z, raw.w};
            bf16x8 tt;
            #pragma unroll
            for (int j = 0; j < 4; ++j) {
                float flo = bf2f((ushort)(wv[j] & 0xffffu)) + b3r[kc][2 * j];
                float fhi = bf2f((ushort)(wv[j] >> 16))    + b3r[kc][2 * j + 1];
                tt[2 * j]     = (short)f2bf(fmaxf(flo, 0.0f));
                tt[2 * j + 1] = (short)f2bf(fmaxf(fhi, 0.0f));
            }
            A[kc] = tt;
        }
        f32x4 acc[8] = {};
        #pragma unroll
        for (int kc = 0; kc < 2; ++kc)
            #pragma unroll
            for (int cb = 0; cb < 8; ++cb)
                acc[cb] = __builtin_amdgcn_mfma_f32_16x16x32_bf16(A[kc], B4[kc][cb], acc[cb], 0, 0, 0);

        int g0 = batch[rbase], g15 = batch[rbase + 15];
        if (g0 != curg) { FLUSH(curg); curg = g0; }
        if (g0 == g15) {
            #pragma unroll
            for (int cb = 0; cb < 8; ++cb)
                pacc[cb] += acc[cb][0] + acc[cb][1] + acc[cb][2] + acc[cb][3]
                            + 4.0f * b4r[cb];
        } else {
            FLUSH(curg);
            #pragma unroll
            for (int i = 0; i < 4; ++i) {
                int gi = batch[rbase + lg * 4 + i];
                #pragma unroll
                for (int cb = 0; cb < 8; ++cb)
                    unsafeAtomicAdd(&pooled[gi * 128 + cb * 16 + lm],
                                    acc[cb][i] + b4r[cb]);
            }
            curg = g15;
        }
    }
    FLUSH(curg);
#undef FLUSH
}

// ================= head =================
__global__ void head_kernel(
    const float* __restrict__ pooled, const int* __restrict__ batch,
    const float* __restrict__ Wfc, const float* __restrict__ bfc,
    float* __restrict__ out)
{
    int g = threadIdx.x;
    if (g >= NUM_GRAPHS) return;

    int lo = 0, hi = N_NODES;
    while (lo < hi) { int mid = (lo + hi) >> 1; if (batch[mid] < g) lo = mid + 1; else hi = mid; }
    int beg = lo;
    lo = 0; hi = N_NODES;
    while (lo < hi) { int mid = (lo + hi) >> 1; if (batch[mid] < g + 1) lo = mid + 1; else hi = mid; }
    int cnt = lo - beg;
    float inv = 1.0f / fmaxf((float)cnt, 1.0f);

    float logits[10];
    for (int o = 0; o < 10; ++o) {
        float acc = 0.0f;
        for (int k = 0; k < 128; ++k)
            acc = fmaf(pooled[g * 128 + k], Wfc[k * 10 + o], acc);
        logits[o] = acc * inv + bfc[o];
    }
    float m = -INFINITY;
    for (int o = 0; o < 10; ++o) m = fmaxf(m, logits[o]);
    float s = 0.0f;
    for (int o = 0; o < 10; ++o) s += expf(logits[o] - m);
    float ls = logf(s);
    for (int o = 0; o < 10; ++o) out[g * 10 + o] = logits[o] - m - ls;
}

extern "C" void kernel_launch(void* const* d_in, const int* in_sizes, int n_in,
                              void* d_out, int out_size, void* d_ws, size_t ws_size,
                              hipStream_t stream)
{
    const float* x     = (const float*)d_in[0];
    const int*   ei    = (const int*)d_in[1];
    const int*   src   = ei;
    const int*   dst   = ei + N_EDGES;
    const int*   batch = (const int*)d_in[2];
    const float* W1  = (const float*)d_in[3];
    const float* b1  = (const float*)d_in[4];
    const float* W2  = (const float*)d_in[5];
    const float* b2  = (const float*)d_in[6];
    const float* W3  = (const float*)d_in[7];
    const float* b3  = (const float*)d_in[8];
    const float* W4  = (const float*)d_in[9];
    const float* b4  = (const float*)d_in[10];
    const float* Wfc = (const float*)d_in[11];
    const float* bfc = (const float*)d_in[12];
    float* out = (float*)d_out;

    char* ws = (char*)d_ws;
    unsigned char* yfp8 = (unsigned char*)(ws);              // 6.4 MB (fp8 y, pre-act)
    unsigned char* zfp8 = (unsigned char*)(ws + 6400000);    // 6.4 MB (fp8 z, pre-act)
    ushort* yagg  = (ushort*)(ws + 12800000);                // 12.8 MB (bf16)
    ushort* zagg  = (ushort*)(ws + 25600000);                // 12.8 MB (bf16)
    int*  esrc    = (int*) (ws + 38400000);                  // 6.4 MB
    uint* epack   = (uint*)(ws + 44800000);                  // 6.4 MB
    int*  rowptr  = (int*) (ws + 51200000);                  // 400,004 B
    int*  bcount  = (int*) (ws + 51600016);                  // 613,088 B
    int*  basetab = (int*) (ws + 52213104);                  // 613,088 B
    int*  btot    = (int*) (ws + 52826192);                  // 784 B
    int*  gbase   = (int*) (ws + 52826976);                  // 788 B
    float* pooled = (float*)(ws + 52827776);                 // 32 KB

    // ---- K1: coarse hist + gemm1 (fp8 out) ----
    k1_hist_gemm<<<NB1 + GEMM_GS, 256, 0, stream>>>(dst, bcount, x, W1, yfp8);
    // ---- CSR build ----
    p2a_scan<<<NBUCK, 256, 0, stream>>>(bcount, basetab, btot);
    p2b_scan<<<1, 256, 0, stream>>>(btot, gbase, pooled);
    p3_partition<<<NB1, 256, 0, stream>>>(src, dst, basetab, gbase, epack);
    p4_fine<<<NBUCK, 256, 0, stream>>>(epack, gbase, rowptr, esrc);

    // ---- layer 1 ----
    agg_fp8<<<(N_NODES + AGG_NPB - 1) / AGG_NPB, 256, 0, stream>>>(
        (const uint2*)yfp8, (uint4*)yagg, rowptr, esrc);
    fused_mid<<<GEMM_GS, 256, 0, stream>>>(yagg, b1, W2, b2, W3, zfp8);

    // ---- layer 2 ----
    agg_fp8<<<(N_NODES + AGG_NPB - 1) / AGG_NPB, 256, 0, stream>>>(
        (const uint2*)zfp8, (uint4*)zagg, rowptr, esrc);
    {
        const int NT = N_NODES / 16;   // 6250
        const int TPW = 4;
        int blocks = (NT + 4 * TPW - 1) / (4 * TPW);   // 391
        k4_mfma_pool<<<blocks, 256, 0, stream>>>(zagg, b3, W4, b4, batch, pooled);
    }

    head_kernel<<<1, 64, 0, stream>>>(pooled, batch, Wfc, bfc, out);
}

// Round 16
// 170.857 us; speedup vs baseline: 1.0653x; 1.0158x over previous
//
#include <hip/hip_runtime.h>
#include <cmath>

#define N_NODES    100000
#define N_EDGES    1600000
#define NUM_GRAPHS 64

// counting-sort geometry
#define BUCK_W     512                               // nodes per coarse bucket
#define NBUCK      196                               // ceil(100000/512)
#define EPB        2048                              // edges per partition block
#define NB1        782                               // ceil(1600000/2048)
#define GEMM_GS    782                               // grid-stride blocks for gemm1/fused_mid
#define AGG_NPB    64                                // nodes per agg block (1563 blocks)

typedef __attribute__((ext_vector_type(8))) short bf16x8;
typedef __attribute__((ext_vector_type(4))) float f32x4;
typedef __attribute__((ext_vector_type(2))) float f32x2;

__device__ __forceinline__ ushort f2bf(float x) {
    union { float f; uint u; } v; v.f = x;
    uint r = v.u + 0x7fffu + ((v.u >> 16) & 1u);
    return (ushort)(r >> 16);
}
__device__ __forceinline__ float bf2f(ushort u) {
    union { uint u; float f; } v; v.u = ((uint)u) << 16;
    return v.f;
}
// f32 -> fp8 e4m3 (OCP) via HW converter, low byte
__device__ __forceinline__ unsigned char f2fp8(float v) {
    int p = __builtin_amdgcn_cvt_pk_fp8_f32(v, v, 0, false);
    return (unsigned char)(p & 0xFF);
}
// accumulate 8 fp8 channels (one uint2) into f32 accumulators
__device__ __forceinline__ void accum8_fp8(float* a, uint2 V) {
    f32x2 d0 = __builtin_amdgcn_cvt_pk_f32_fp8((int)V.x, false);
    f32x2 d1 = __builtin_amdgcn_cvt_pk_f32_fp8((int)V.x, true);
    f32x2 d2 = __builtin_amdgcn_cvt_pk_f32_fp8((int)V.y, false);
    f32x2 d3 = __builtin_amdgcn_cvt_pk_f32_fp8((int)V.y, true);
    a[0] += d0.x; a[1] += d0.y; a[2] += d1.x; a[3] += d1.y;
    a[4] += d2.x; a[5] += d2.y; a[6] += d3.x; a[7] += d3.y;
}

// ========== K1: coarse histogram (blocks [0,NB1)) + gemm1 grid-stride (rest) ==========
// gemm1 emits y in fp8 e4m3 (the gathered representation, pre-activation).
__global__ __launch_bounds__(256) void k1_hist_gemm(
    const int* __restrict__ dst, int* __restrict__ bcount,
    const float* __restrict__ x, const float* __restrict__ W1,
    unsigned char* __restrict__ y8)
{
    if (blockIdx.x < NB1) {
        __shared__ int shist[NBUCK];
        int tid = threadIdx.x;
        for (int i = tid; i < NBUCK; i += 256) shist[i] = 0;
        __syncthreads();
        int e0 = blockIdx.x * EPB + tid;
        #pragma unroll
        for (int k = 0; k < EPB / 256; ++k) {
            int e = e0 + k * 256;
            if (e < N_EDGES) atomicAdd(&shist[dst[e] >> 9], 1);
        }
        __syncthreads();
        for (int i = tid; i < NBUCK; i += 256)
            bcount[blockIdx.x * NBUCK + i] = shist[i];
        return;
    }
    int bid = blockIdx.x - NB1;
    int lane = threadIdx.x & 63, wave = threadIdx.x >> 6;
    int lg = lane >> 4, lm = lane & 15;

    bf16x8 Bf[4][4];
    #pragma unroll
    for (int kc = 0; kc < 4; ++kc)
        #pragma unroll
        for (int cb = 0; cb < 4; ++cb) {
            bf16x8 t;
            #pragma unroll
            for (int i = 0; i < 8; ++i)
                t[i] = (short)f2bf(W1[(kc * 32 + lg * 8 + i) * 64 + cb * 16 + lm]);
            Bf[kc][cb] = t;
        }

    const int ntiles = N_NODES / 16;   // 6250
    for (int tile = bid * 4 + wave; tile < ntiles; tile += GEMM_GS * 4) {
        int r = tile * 16 + lm;
        f32x4 acc[4] = {};
        #pragma unroll
        for (int kc = 0; kc < 4; ++kc) {
            const float* p = x + (size_t)r * 128 + kc * 32 + lg * 8;
            float4 a0 = *(const float4*)p;
            float4 a1 = *(const float4*)(p + 4);
            bf16x8 af;
            af[0] = (short)f2bf(a0.x); af[1] = (short)f2bf(a0.y);
            af[2] = (short)f2bf(a0.z); af[3] = (short)f2bf(a0.w);
            af[4] = (short)f2bf(a1.x); af[5] = (short)f2bf(a1.y);
            af[6] = (short)f2bf(a1.z); af[7] = (short)f2bf(a1.w);
            #pragma unroll
            for (int cb = 0; cb < 4; ++cb)
                acc[cb] = __builtin_amdgcn_mfma_f32_16x16x32_bf16(af, Bf[kc][cb], acc[cb], 0, 0, 0);
        }
        #pragma unroll
        for (int cb = 0; cb < 4; ++cb)
            #pragma unroll
            for (int i = 0; i < 4; ++i)
                y8[(size_t)(tile * 16 + lg * 4 + i) * 64 + cb * 16 + lm] = f2fp8(acc[cb][i]);
    }
}

// ========== P2a: per-bucket exclusive scan over NB1 block counts (parallel) ==========
#define SCH 4   // 256*4 = 1024 >= NB1
__global__ __launch_bounds__(256) void p2a_scan(
    const int* __restrict__ bcount, int* __restrict__ basetab,
    int* __restrict__ btot)
{
    __shared__ int sh[256];
    int b = blockIdx.x, tid = threadIdx.x;
    int v[SCH];
    int tsum = 0;
    #pragma unroll
    for (int j = 0; j < SCH; ++j) {
        int blk = tid * SCH + j;
        v[j] = (blk < NB1) ? bcount[(size_t)blk * NBUCK + b] : 0;
        tsum += v[j];
    }
    sh[tid] = tsum;
    __syncthreads();
    for (int off = 1; off < 256; off <<= 1) {
        int t = (tid >= off) ? sh[tid - off] : 0;
        __syncthreads();
        sh[tid] += t;
        __syncthreads();
    }
    if (tid == 255) btot[b] = sh[255];
    int excl = sh[tid] - tsum;
    #pragma unroll
    for (int j = 0; j < SCH; ++j) {
        int blk = tid * SCH + j;
        if (blk < NB1) basetab[(size_t)b * NB1 + blk] = excl;
        excl += v[j];
    }
}

// ========== P2b: exclusive scan of bucket totals -> gbase ; zero pooled ==========
__global__ __launch_bounds__(256) void p2b_scan(
    const int* __restrict__ btot, int* __restrict__ gbase,
    float* __restrict__ pooled)
{
    int tid = threadIdx.x;
    for (int i = tid; i < NUM_GRAPHS * 128; i += 256) pooled[i] = 0.0f;
    __shared__ int v[NBUCK];
    for (int j = tid; j < NBUCK; j += 256) v[j] = btot[j];
    __syncthreads();
    if (tid == 0) {
        int run = 0;
        for (int j = 0; j < NBUCK; ++j) { int t = v[j]; v[j] = run; run += t; }
        gbase[NBUCK] = run;   // == N_EDGES
    }
    __syncthreads();
    for (int j = tid; j < NBUCK; j += 256) gbase[j] = v[j];
}

// ========== P3 v2: LDS counting-sort, then bucket-ordered COALESCED writes ==========
// global addr of LDS-ordered index j = sbase[bin(j)] + j  (affine in j within segment)
__global__ __launch_bounds__(256) void p3_partition(
    const int* __restrict__ src, const int* __restrict__ dst,
    const int* __restrict__ basetab, const int* __restrict__ gbase,
    uint* __restrict__ epack)
{
    __shared__ int shist[NBUCK];          // hist -> exclusive seg starts
    __shared__ int scur[NBUCK];           // scatter cursors
    __shared__ int sbase[NBUCK];          // global base - LDS seg start
    __shared__ uint lbuf[EPB];            // 8 KB packed edges, bucket-sorted
    __shared__ unsigned char lbin[EPB];   // 2 KB bucket id per slot

    int blk = blockIdx.x, tid = threadIdx.x;
    int cnt = min(EPB, N_EDGES - blk * EPB);

    for (int i = tid; i < NBUCK; i += 256) shist[i] = 0;
    __syncthreads();

    uint mypack[EPB / 256];
    int  mybin[EPB / 256];
    #pragma unroll
    for (int k = 0; k < EPB / 256; ++k) {
        int e = blk * EPB + tid + k * 256;
        if (e < N_EDGES) {
            int d = dst[e], s = src[e];
            mybin[k] = d >> 9;
            mypack[k] = ((uint)(d & 511) << 17) | (uint)s;
            atomicAdd(&shist[mybin[k]], 1);
        } else mybin[k] = -1;
    }
    __syncthreads();
    if (tid == 0) {
        int run = 0;
        for (int i = 0; i < NBUCK; ++i) { int t = shist[i]; shist[i] = run; run += t; }
    }
    __syncthreads();
    for (int i = tid; i < NBUCK; i += 256) {
        scur[i] = shist[i];
        sbase[i] = basetab[(size_t)i * NB1 + blk] + gbase[i] - shist[i];
    }
    __syncthreads();
    #pragma unroll
    for (int k = 0; k < EPB / 256; ++k) {
        if (mybin[k] >= 0) {
            int p = atomicAdd(&scur[mybin[k]], 1);
            lbuf[p] = mypack[k];
            lbin[p] = (unsigned char)mybin[k];
        }
    }
    __syncthreads();
    for (int j = tid; j < cnt; j += 256) {
        int bin = lbin[j];
        epack[sbase[bin] + j] = lbuf[j];
    }
}

// ========== P4: per-bucket fine CSR (rowptr + esrc), all LDS ==========
__global__ __launch_bounds__(256) void p4_fine(
    const uint* __restrict__ epack, const int* __restrict__ gbase,
    int* __restrict__ rowptr, int* __restrict__ esrc)
{
    __shared__ int hist[BUCK_W];
    int b = blockIdx.x, tid = threadIdx.x;
    int beg = gbase[b], end = gbase[b + 1];
    for (int i = tid; i < BUCK_W; i += 256) hist[i] = 0;
    __syncthreads();
    for (int e = beg + tid; e < end; e += 256)
        atomicAdd(&hist[epack[e] >> 17], 1);
    __syncthreads();
    if (tid == 0) {
        int run = 0;
        for (int i = 0; i < BUCK_W; ++i) { int t = hist[i]; hist[i] = run; run += t; }
    }
    __syncthreads();
    for (int i = tid; i < BUCK_W; i += 256) {
        int n = b * BUCK_W + i;
        if (n < N_NODES) rowptr[n] = beg + hist[i];
    }
    if (b == NBUCK - 1 && tid == 0) rowptr[N_NODES] = end;
    __syncthreads();
    for (int e = beg + tid; e < end; e += 256) {
        uint v = epack[e];
        int slot = beg + atomicAdd(&hist[v >> 17], 1);
        esrc[slot] = (int)(v & 0x1FFFFu);
    }
}

// ====== gather fp8 (v4 structure): 8-lane group per node, work-steal pool ======
// Input rows are 64 ch fp8 = 64 B; each lane loads uint2 (8 ch), f32-accumulates,
// output written as bf16 (128 B rows) for the MFMA consumers.
__global__ __launch_bounds__(256) void agg_fp8(
    const uint2* __restrict__ in8, uint4* __restrict__ out4,
    const int* __restrict__ rowptr, const int* __restrict__ esrc)
{
    __shared__ int pool;
    if (threadIdx.x == 0) pool = 0;
    __syncthreads();

    int sub = threadIdx.x & 7;
    int wl  = threadIdx.x & 63;
    int base = blockIdx.x * AGG_NPB;
    int nmax = min(AGG_NPB, N_NODES - base);

    for (;;) {
        int n = 0;
        if (sub == 0) n = atomicAdd(&pool, 1);
        n = __shfl(n, wl & 56, 64);    // broadcast from group leader
        if (n >= nmax) break;
        int node = base + n;

        float a[8] = {0, 0, 0, 0, 0, 0, 0, 0};
        accum8_fp8(a, in8[(size_t)node * 8 + sub]);   // self term

        int e = rowptr[node], end = rowptr[node + 1];
        for (; e + 8 <= end; e += 8) {
            int i0 = esrc[e],     i1 = esrc[e + 1], i2 = esrc[e + 2], i3 = esrc[e + 3];
            int i4 = esrc[e + 4], i5 = esrc[e + 5], i6 = esrc[e + 6], i7 = esrc[e + 7];
            uint2 v0 = in8[(size_t)i0 * 8 + sub];
            uint2 v1 = in8[(size_t)i1 * 8 + sub];
            uint2 v2 = in8[(size_t)i2 * 8 + sub];
            uint2 v3 = in8[(size_t)i3 * 8 + sub];
            uint2 v4 = in8[(size_t)i4 * 8 + sub];
            uint2 v5 = in8[(size_t)i5 * 8 + sub];
            uint2 v6 = in8[(size_t)i6 * 8 + sub];
            uint2 v7 = in8[(size_t)i7 * 8 + sub];
            accum8_fp8(a, v0); accum8_fp8(a, v1); accum8_fp8(a, v2); accum8_fp8(a, v3);
            accum8_fp8(a, v4); accum8_fp8(a, v5); accum8_fp8(a, v6); accum8_fp8(a, v7);
        }
        if (e + 4 <= end) {
            int i0 = esrc[e], i1 = esrc[e + 1], i2 = esrc[e + 2], i3 = esrc[e + 3];
            uint2 v0 = in8[(size_t)i0 * 8 + sub];
            uint2 v1 = in8[(size_t)i1 * 8 + sub];
            uint2 v2 = in8[(size_t)i2 * 8 + sub];
            uint2 v3 = in8[(size_t)i3 * 8 + sub];
            accum8_fp8(a, v0); accum8_fp8(a, v1); accum8_fp8(a, v2); accum8_fp8(a, v3);
            e += 4;
        }
        for (; e < end; ++e)
            accum8_fp8(a, in8[(size_t)esrc[e] * 8 + sub]);

        uint4 o;
        o.x = (uint)f2bf(a[0]) | ((uint)f2bf(a[1]) << 16);
        o.y = (uint)f2bf(a[2]) | ((uint)f2bf(a[3]) << 16);
        o.z = (uint)f2bf(a[4]) | ((uint)f2bf(a[5]) << 16);
        o.w = (uint)f2bf(a[6]) | ((uint)f2bf(a[7]) << 16);
        out4[(size_t)node * 8 + sub] = o;
    }
}

// ===== fused_mid: t=relu(yagg+b1); h1=relu(t@W2+b2); z=h1@W3 (bf16 MFMA, fp8 out) =====
__global__ __launch_bounds__(256) void fused_mid(
    const ushort* __restrict__ yagg, const float* __restrict__ b1,
    const float* __restrict__ W2, const float* __restrict__ b2,
    const float* __restrict__ W3, unsigned char* __restrict__ z8)
{
    __shared__ __align__(16) float trs[4][16 * 68];
    int lane = threadIdx.x & 63, wave = threadIdx.x >> 6;
    int lg = lane >> 4, lm = lane & 15;

    bf16x8 B2[2][4], B3[2][4];
    #pragma unroll
    for (int kc = 0; kc < 2; ++kc)
        #pragma unroll
        for (int cb = 0; cb < 4; ++cb) {
            bf16x8 t2, t3;
            #pragma unroll
            for (int i = 0; i < 8; ++i) {
                int k = kc * 32 + lg * 8 + i;
                int cc = cb * 16 + lm;
                t2[i] = (short)f2bf(W2[k * 64 + cc]);
                t3[i] = (short)f2bf(W3[k * 64 + cc]);
            }
            B2[kc][cb] = t2; B3[kc][cb] = t3;
        }
    float b1r[2][8];
    #pragma unroll
    for (int kc = 0; kc < 2; ++kc)
        #pragma unroll
        for (int i = 0; i < 8; ++i)
            b1r[kc][i] = b1[kc * 32 + lg * 8 + i];
    float b2r[4];
    #pragma unroll
    for (int cb = 0; cb < 4; ++cb) b2r[cb] = b2[cb * 16 + lm];

    const int ntiles = N_NODES / 16;
    for (int tile = blockIdx.x * 4 + wave; tile < ntiles; tile += GEMM_GS * 4) {
        int r = tile * 16 + lm;
        bf16x8 A1[2];
        #pragma unroll
        for (int kc = 0; kc < 2; ++kc) {
            uint4 raw = *(const uint4*)(yagg + (size_t)r * 64 + kc * 32 + lg * 8);
            uint w[4] = {raw.x, raw.y, raw.z, raw.w};
            bf16x8 t;
            #pragma unroll
            for (int j = 0; j < 4; ++j) {
                float flo = bf2f((ushort)(w[j] & 0xffffu)) + b1r[kc][2 * j];
                float fhi = bf2f((ushort)(w[j] >> 16)) + b1r[kc][2 * j + 1];
                t[2 * j]     = (short)f2bf(fmaxf(flo, 0.0f));
                t[2 * j + 1] = (short)f2bf(fmaxf(fhi, 0.0f));
            }
            A1[kc] = t;
        }
        f32x4 acc[4] = {};
        #pragma unroll
        for (int kc = 0; kc < 2; ++kc)
            #pragma unroll
            for (int cb = 0; cb < 4; ++cb)
                acc[cb] = __builtin_amdgcn_mfma_f32_16x16x32_bf16(A1[kc], B2[kc][cb], acc[cb], 0, 0, 0);
        #pragma unroll
        for (int cb = 0; cb < 4; ++cb)
            #pragma unroll
            for (int i = 0; i < 4; ++i)
                trs[wave][(lg * 4 + i) * 68 + cb * 16 + lm] = fmaxf(acc[cb][i] + b2r[cb], 0.0f);
        bf16x8 A2[2];
        #pragma unroll
        for (int kc = 0; kc < 2; ++kc) {
            const float* p = &trs[wave][lm * 68 + kc * 32 + lg * 8];
            float4 u0 = *(const float4*)p;
            float4 u1 = *(const float4*)(p + 4);
            bf16x8 t;
            t[0] = (short)f2bf(u0.x); t[1] = (short)f2bf(u0.y);
            t[2] = (short)f2bf(u0.z); t[3] = (short)f2bf(u0.w);
            t[4] = (short)f2bf(u1.x); t[5] = (short)f2bf(u1.y);
            t[6] = (short)f2bf(u1.z); t[7] = (short)f2bf(u1.w);
            A2[kc] = t;
        }
        f32x4 acc2[4] = {};
        #pragma unroll
        for (int kc = 0; kc < 2; ++kc)
            #pragma unroll
            for (int cb = 0; cb < 4; ++cb)
                acc2[cb] = __builtin_amdgcn_mfma_f32_16x16x32_bf16(A2[kc], B3[kc][cb], acc2[cb], 0, 0, 0);
        #pragma unroll
        for (int cb = 0; cb < 4; ++cb)
            #pragma unroll
            for (int i = 0; i < 4; ++i)
                z8[(size_t)(tile * 16 + lg * 4 + i) * 64 + cb * 16 + lm] = f2fp8(acc2[cb][i]);
    }
}

// ===== k4 MFMA: o = relu(zagg+b3)@W4+b4 ; pooled[batch[r]] += o =====
__global__ __launch_bounds__(256) void k4_mfma_pool(
    const ushort* __restrict__ zagg, const float* __restrict__ b3,
    const float* __restrict__ W4, const float* __restrict__ b4,
    const int* __restrict__ batch, float* __restrict__ pooled)
{
    int lane = threadIdx.x & 63, wave = threadIdx.x >> 6;
    int lg = lane >> 4, lm = lane & 15;

    bf16x8 B4[2][8];
    #pragma unroll
    for (int kc = 0; kc < 2; ++kc)
        #pragma unroll
        for (int cb = 0; cb < 8; ++cb) {
            bf16x8 t;
            #pragma unroll
            for (int i = 0; i < 8; ++i)
                t[i] = (short)f2bf(W4[(kc * 32 + lg * 8 + i) * 128 + cb * 16 + lm]);
            B4[kc][cb] = t;
        }
    float b3r[2][8];
    #pragma unroll
    for (int kc = 0; kc < 2; ++kc)
        #pragma unroll
        for (int i = 0; i < 8; ++i)
            b3r[kc][i] = b3[kc * 32 + lg * 8 + i];
    float b4r[8];
    #pragma unroll
    for (int cb = 0; cb < 8; ++cb) b4r[cb] = b4[cb * 16 + lm];

    const int NT = N_NODES / 16;   // 6250
    const int TPW = 4;
    int w = blockIdx.x * 4 + wave;
    int t0 = w * TPW;
    if (t0 >= NT) return;
    int t1 = min(t0 + TPW, NT);

    float pacc[8] = {0, 0, 0, 0, 0, 0, 0, 0};
    int curg = batch[t0 * 16];

#define FLUSH(G) do {                                                     \
        _Pragma("unroll")                                                 \
        for (int cb = 0; cb < 8; ++cb) {                                  \
            float v = pacc[cb];                                           \
            v += __shfl_xor(v, 16, 64);                                   \
            v += __shfl_xor(v, 32, 64);                                   \
            if (lane < 16) unsafeAtomicAdd(&pooled[(G) * 128 + cb * 16 + lm], v); \
            pacc[cb] = 0.0f;                                              \
        }                                                                 \
    } while (0)

    for (int t = t0; t < t1; ++t) {
        int rbase = t * 16;
        int r = rbase + lm;
        bf16x8 A[2];
        #pragma unroll
        for (int kc = 0; kc < 2; ++kc) {
            uint4 raw = *(const uint4*)(zagg + (size_t)r * 64 + kc * 32 + lg * 8);
            uint wv[4] = {raw.x, raw.y, raw.z, raw.w};
            bf16x8 tt;
            #pragma unroll
            for (int j = 0; j < 4; ++j) {
                float flo = bf2f((ushort)(wv[j] & 0xffffu)) + b3r[kc][2 * j];
                float fhi = bf2f((ushort)(wv[j] >> 16))    + b3r[kc][2 * j + 1];
                tt[2 * j]     = (short)f2bf(fmaxf(flo, 0.0f));
                tt[2 * j + 1] = (short)f2bf(fmaxf(fhi, 0.0f));
            }
            A[kc] = tt;
        }
        f32x4 acc[8] = {};
        #pragma unroll
        for (int kc = 0; kc < 2; ++kc)
            #pragma unroll
            for (int cb = 0; cb < 8; ++cb)
                acc[cb] = __builtin_amdgcn_mfma_f32_16x16x32_bf16(A[kc], B4[kc][cb], acc[cb], 0, 0, 0);

        int g0 = batch[rbase], g15 = batch[rbase + 15];
        if (g0 != curg) { FLUSH(curg); curg = g0; }
        if (g0 == g15) {
            #pragma unroll
            for (int cb = 0; cb < 8; ++cb)
                pacc[cb] += acc[cb][0] + acc[cb][1] + acc[cb][2] + acc[cb][3]
                            + 4.0f * b4r[cb];
        } else {
            FLUSH(curg);
            #pragma unroll
            for (int i = 0; i < 4; ++i) {
                int gi = batch[rbase + lg * 4 + i];
                #pragma unroll
                for (int cb = 0; cb < 8; ++cb)
                    unsafeAtomicAdd(&pooled[gi * 128 + cb * 16 + lm],
                                    acc[cb][i] + b4r[cb]);
            }
            curg = g15;
        }
    }
    FLUSH(curg);
#undef FLUSH
}

// ================= head =================
__global__ void head_kernel(
    const float* __restrict__ pooled, const int* __restrict__ batch,
    const float* __restrict__ Wfc, const float* __restrict__ bfc,
    float* __restrict__ out)
{
    int g = threadIdx.x;
    if (g >= NUM_GRAPHS) return;

    int lo = 0, hi = N_NODES;
    while (lo < hi) { int mid = (lo + hi) >> 1; if (batch[mid] < g) lo = mid + 1; else hi = mid; }
    int beg = lo;
    lo = 0; hi = N_NODES;
    while (lo < hi) { int mid = (lo + hi) >> 1; if (batch[mid] < g + 1) lo = mid + 1; else hi = mid; }
    int cnt = lo - beg;
    float inv = 1.0f / fmaxf((float)cnt, 1.0f);

    float logits[10];
    for (int o = 0; o < 10; ++o) {
        float acc = 0.0f;
        for (int k = 0; k < 128; ++k)
            acc = fmaf(pooled[g * 128 + k], Wfc[k * 10 + o], acc);
        logits[o] = acc * inv + bfc[o];
    }
    float m = -INFINITY;
    for (int o = 0; o < 10; ++o) m = fmaxf(m, logits[o]);
    float s = 0.0f;
    for (int o = 0; o < 10; ++o) s += expf(logits[o] - m);
    float ls = logf(s);
    for (int o = 0; o < 10; ++o) out[g * 10 + o] = logits[o] - m - ls;
}

extern "C" void kernel_launch(void* const* d_in, const int* in_sizes, int n_in,
                              void* d_out, int out_size, void* d_ws, size_t ws_size,
                              hipStream_t stream)
{
    const float* x     = (const float*)d_in[0];
    const int*   ei    = (const int*)d_in[1];
    const int*   src   = ei;
    const int*   dst   = ei + N_EDGES;
    const int*   batch = (const int*)d_in[2];
    const float* W1  = (const float*)d_in[3];
    const float* b1  = (const float*)d_in[4];
    const float* W2  = (const float*)d_in[5];
    const float* b2  = (const float*)d_in[6];
    const float* W3  = (const float*)d_in[7];
    const float* b3  = (const float*)d_in[8];
    const float* W4  = (const float*)d_in[9];
    const float* b4  = (const float*)d_in[10];
    const float* Wfc = (const float*)d_in[11];
    const float* bfc = (const float*)d_in[12];
    float* out = (float*)d_out;

    char* ws = (char*)d_ws;
    unsigned char* yfp8 = (unsigned char*)(ws);              // 6.4 MB (fp8 y, pre-act)
    unsigned char* zfp8 = (unsigned char*)(ws + 6400000);    // 6.4 MB (fp8 z, pre-act)
    ushort* yagg  = (ushort*)(ws + 12800000);                // 12.8 MB (bf16)
    ushort* zagg  = (ushort*)(ws + 25600000);                // 12.8 MB (bf16)
    int*  esrc    = (int*) (ws + 38400000);                  // 6.4 MB
    uint* epack   = (uint*)(ws + 44800000);                  // 6.4 MB
    int*  rowptr  = (int*) (ws + 51200000);                  // 400,004 B
    int*  bcount  = (int*) (ws + 51600016);                  // 613,088 B
    int*  basetab = (int*) (ws + 52213104);                  // 613,088 B
    int*  btot    = (int*) (ws + 52826192);                  // 784 B
    int*  gbase   = (int*) (ws + 52826976);                  // 788 B
    float* pooled = (float*)(ws + 52827776);                 // 32 KB

    // ---- K1: coarse hist + gemm1 (fp8 out) ----
    k1_hist_gemm<<<NB1 + GEMM_GS, 256, 0, stream>>>(dst, bcount, x, W1, yfp8);
    // ---- CSR build ----
    p2a_scan<<<NBUCK, 256, 0, stream>>>(bcount, basetab, btot);
    p2b_scan<<<1, 256, 0, stream>>>(btot, gbase, pooled);
    p3_partition<<<NB1, 256, 0, stream>>>(src, dst, basetab, gbase, epack);
    p4_fine<<<NBUCK, 256, 0, stream>>>(epack, gbase, rowptr, esrc);

    // ---- layer 1 ----
    agg_fp8<<<(N_NODES + AGG_NPB - 1) / AGG_NPB, 256, 0, stream>>>(
        (const uint2*)yfp8, (uint4*)yagg, rowptr, esrc);
    fused_mid<<<GEMM_GS, 256, 0, stream>>>(yagg, b1, W2, b2, W3, zfp8);

    // ---- layer 2 ----
    agg_fp8<<<(N_NODES + AGG_NPB - 1) / AGG_NPB, 256, 0, stream>>>(
        (const uint2*)zfp8, (uint4*)zagg, rowptr, esrc);
    {
        const int NT = N_NODES / 16;   // 6250
        const int TPW = 4;
        int blocks = (NT + 4 * TPW - 1) / (4 * TPW);   // 391
        k4_mfma_pool<<<blocks, 256, 0, stream>>>(zagg, b3, W4, b4, batch, pooled);
    }

    head_kernel<<<1, 64, 0, stream>>>(pooled, batch, Wfc, bfc, out);
}

// Round 17
// 169.366 us; speedup vs baseline: 1.0747x; 1.0088x over previous
//
#include <hip/hip_runtime.h>
#include <cmath>

#define N_NODES    100000
#define N_EDGES    1600000
#define NUM_GRAPHS 64

// counting-sort geometry
#define BUCK_W     512                               // nodes per coarse bucket
#define NBUCK      196                               // ceil(100000/512)
#define EPB        2048                              // edges per partition block
#define NB1        782                               // ceil(1600000/2048)
#define GEMM_GS    782                               // grid-stride blocks for gemm1/fused_mid
#define AGG_NPB    32                                // nodes per agg block (3125 blocks)

typedef __attribute__((ext_vector_type(8))) short bf16x8;
typedef __attribute__((ext_vector_type(4))) float f32x4;
typedef __attribute__((ext_vector_type(2))) float f32x2;

__device__ __forceinline__ ushort f2bf(float x) {
    union { float f; uint u; } v; v.f = x;
    uint r = v.u + 0x7fffu + ((v.u >> 16) & 1u);
    return (ushort)(r >> 16);
}
__device__ __forceinline__ float bf2f(ushort u) {
    union { uint u; float f; } v; v.u = ((uint)u) << 16;
    return v.f;
}
// f32 -> fp8 e4m3 (OCP) via HW converter, low byte
__device__ __forceinline__ unsigned char f2fp8(float v) {
    int p = __builtin_amdgcn_cvt_pk_fp8_f32(v, v, 0, false);
    return (unsigned char)(p & 0xFF);
}
// accumulate 8 fp8 channels (one uint2) into f32 accumulators
__device__ __forceinline__ void accum8_fp8(float* a, uint2 V) {
    f32x2 d0 = __builtin_amdgcn_cvt_pk_f32_fp8((int)V.x, false);
    f32x2 d1 = __builtin_amdgcn_cvt_pk_f32_fp8((int)V.x, true);
    f32x2 d2 = __builtin_amdgcn_cvt_pk_f32_fp8((int)V.y, false);
    f32x2 d3 = __builtin_amdgcn_cvt_pk_f32_fp8((int)V.y, true);
    a[0] += d0.x; a[1] += d0.y; a[2] += d1.x; a[3] += d1.y;
    a[4] += d2.x; a[5] += d2.y; a[6] += d3.x; a[7] += d3.y;
}

// ========== K1: coarse histogram (blocks [0,NB1)) + gemm1 grid-stride (rest) ==========
// gemm1 emits y in fp8 e4m3 (the gathered representation, pre-activation).
__global__ __launch_bounds__(256) void k1_hist_gemm(
    const int* __restrict__ dst, int* __restrict__ bcount,
    const float* __restrict__ x, const float* __restrict__ W1,
    unsigned char* __restrict__ y8)
{
    if (blockIdx.x < NB1) {
        __shared__ int shist[NBUCK];
        int tid = threadIdx.x;
        for (int i = tid; i < NBUCK; i += 256) shist[i] = 0;
        __syncthreads();
        int e0 = blockIdx.x * EPB + tid;
        #pragma unroll
        for (int k = 0; k < EPB / 256; ++k) {
            int e = e0 + k * 256;
            if (e < N_EDGES) atomicAdd(&shist[dst[e] >> 9], 1);
        }
        __syncthreads();
        for (int i = tid; i < NBUCK; i += 256)
            bcount[blockIdx.x * NBUCK + i] = shist[i];
        return;
    }
    int bid = blockIdx.x - NB1;
    int lane = threadIdx.x & 63, wave = threadIdx.x >> 6;
    int lg = lane >> 4, lm = lane & 15;

    bf16x8 Bf[4][4];
    #pragma unroll
    for (int kc = 0; kc < 4; ++kc)
        #pragma unroll
        for (int cb = 0; cb < 4; ++cb) {
            bf16x8 t;
            #pragma unroll
            for (int i = 0; i < 8; ++i)
                t[i] = (short)f2bf(W1[(kc * 32 + lg * 8 + i) * 64 + cb * 16 + lm]);
            Bf[kc][cb] = t;
        }

    const int ntiles = N_NODES / 16;   // 6250
    for (int tile = bid * 4 + wave; tile < ntiles; tile += GEMM_GS * 4) {
        int r = tile * 16 + lm;
        f32x4 acc[4] = {};
        #pragma unroll
        for (int kc = 0; kc < 4; ++kc) {
            const float* p = x + (size_t)r * 128 + kc * 32 + lg * 8;
            float4 a0 = *(const float4*)p;
            float4 a1 = *(const float4*)(p + 4);
            bf16x8 af;
            af[0] = (short)f2bf(a0.x); af[1] = (short)f2bf(a0.y);
            af[2] = (short)f2bf(a0.z); af[3] = (short)f2bf(a0.w);
            af[4] = (short)f2bf(a1.x); af[5] = (short)f2bf(a1.y);
            af[6] = (short)f2bf(a1.z); af[7] = (short)f2bf(a1.w);
            #pragma unroll
            for (int cb = 0; cb < 4; ++cb)
                acc[cb] = __builtin_amdgcn_mfma_f32_16x16x32_bf16(af, Bf[kc][cb], acc[cb], 0, 0, 0);
        }
        #pragma unroll
        for (int cb = 0; cb < 4; ++cb)
            #pragma unroll
            for (int i = 0; i < 4; ++i)
                y8[(size_t)(tile * 16 + lg * 4 + i) * 64 + cb * 16 + lm] = f2fp8(acc[cb][i]);
    }
}

// ========== P2a: per-bucket exclusive scan over NB1 block counts (parallel) ==========
#define SCH 4   // 256*4 = 1024 >= NB1
__global__ __launch_bounds__(256) void p2a_scan(
    const int* __restrict__ bcount, int* __restrict__ basetab,
    int* __restrict__ btot)
{
    __shared__ int sh[256];
    int b = blockIdx.x, tid = threadIdx.x;
    int v[SCH];
    int tsum = 0;
    #pragma unroll
    for (int j = 0; j < SCH; ++j) {
        int blk = tid * SCH + j;
        v[j] = (blk < NB1) ? bcount[(size_t)blk * NBUCK + b] : 0;
        tsum += v[j];
    }
    sh[tid] = tsum;
    __syncthreads();
    for (int off = 1; off < 256; off <<= 1) {
        int t = (tid >= off) ? sh[tid - off] : 0;
        __syncthreads();
        sh[tid] += t;
        __syncthreads();
    }
    if (tid == 255) btot[b] = sh[255];
    int excl = sh[tid] - tsum;
    #pragma unroll
    for (int j = 0; j < SCH; ++j) {
        int blk = tid * SCH + j;
        if (blk < NB1) basetab[(size_t)b * NB1 + blk] = excl;
        excl += v[j];
    }
}

// ========== P2b: exclusive scan of bucket totals -> gbase ; zero pooled ==========
__global__ __launch_bounds__(256) void p2b_scan(
    const int* __restrict__ btot, int* __restrict__ gbase,
    float* __restrict__ pooled)
{
    int tid = threadIdx.x;
    for (int i = tid; i < NUM_GRAPHS * 128; i += 256) pooled[i] = 0.0f;
    __shared__ int v[NBUCK];
    for (int j = tid; j < NBUCK; j += 256) v[j] = btot[j];
    __syncthreads();
    if (tid == 0) {
        int run = 0;
        for (int j = 0; j < NBUCK; ++j) { int t = v[j]; v[j] = run; run += t; }
        gbase[NBUCK] = run;   // == N_EDGES
    }
    __syncthreads();
    for (int j = tid; j < NBUCK; j += 256) gbase[j] = v[j];
}

// ========== P3 v2: LDS counting-sort, then bucket-ordered COALESCED writes ==========
// global addr of LDS-ordered index j = sbase[bin(j)] + j  (affine in j within segment)
__global__ __launch_bounds__(256) void p3_partition(
    const int* __restrict__ src, const int* __restrict__ dst,
    const int* __restrict__ basetab, const int* __restrict__ gbase,
    uint* __restrict__ epack)
{
    __shared__ int shist[NBUCK];          // hist -> exclusive seg starts
    __shared__ int scur[NBUCK];           // scatter cursors
    __shared__ int sbase[NBUCK];          // global base - LDS seg start
    __shared__ uint lbuf[EPB];            // 8 KB packed edges, bucket-sorted
    __shared__ unsigned char lbin[EPB];   // 2 KB bucket id per slot

    int blk = blockIdx.x, tid = threadIdx.x;
    int cnt = min(EPB, N_EDGES - blk * EPB);

    for (int i = tid; i < NBUCK; i += 256) shist[i] = 0;
    __syncthreads();

    uint mypack[EPB / 256];
    int  mybin[EPB / 256];
    #pragma unroll
    for (int k = 0; k < EPB / 256; ++k) {
        int e = blk * EPB + tid + k * 256;
        if (e < N_EDGES) {
            int d = dst[e], s = src[e];
            mybin[k] = d >> 9;
            mypack[k] = ((uint)(d & 511) << 17) | (uint)s;
            atomicAdd(&shist[mybin[k]], 1);
        } else mybin[k] = -1;
    }
    __syncthreads();
    if (tid == 0) {
        int run = 0;
        for (int i = 0; i < NBUCK; ++i) { int t = shist[i]; shist[i] = run; run += t; }
    }
    __syncthreads();
    for (int i = tid; i < NBUCK; i += 256) {
        scur[i] = shist[i];
        sbase[i] = basetab[(size_t)i * NB1 + blk] + gbase[i] - shist[i];
    }
    __syncthreads();
    #pragma unroll
    for (int k = 0; k < EPB / 256; ++k) {
        if (mybin[k] >= 0) {
            int p = atomicAdd(&scur[mybin[k]], 1);
            lbuf[p] = mypack[k];
            lbin[p] = (unsigned char)mybin[k];
        }
    }
    __syncthreads();
    for (int j = tid; j < cnt; j += 256) {
        int bin = lbin[j];
        epack[sbase[bin] + j] = lbuf[j];
    }
}

// ========== P4: per-bucket fine CSR (rowptr + esrc), all LDS ==========
__global__ __launch_bounds__(256) void p4_fine(
    const uint* __restrict__ epack, const int* __restrict__ gbase,
    int* __restrict__ rowptr, int* __restrict__ esrc)
{
    __shared__ int hist[BUCK_W];
    int b = blockIdx.x, tid = threadIdx.x;
    int beg = gbase[b], end = gbase[b + 1];
    for (int i = tid; i < BUCK_W; i += 256) hist[i] = 0;
    __syncthreads();
    for (int e = beg + tid; e < end; e += 256)
        atomicAdd(&hist[epack[e] >> 17], 1);
    __syncthreads();
    if (tid == 0) {
        int run = 0;
        for (int i = 0; i < BUCK_W; ++i) { int t = hist[i]; hist[i] = run; run += t; }
    }
    __syncthreads();
    for (int i = tid; i < BUCK_W; i += 256) {
        int n = b * BUCK_W + i;
        if (n < N_NODES) rowptr[n] = beg + hist[i];
    }
    if (b == NBUCK - 1 && tid == 0) rowptr[N_NODES] = end;
    __syncthreads();
    for (int e = beg + tid; e < end; e += 256) {
        uint v = epack[e];
        int slot = beg + atomicAdd(&hist[v >> 17], 1);
        esrc[slot] = (int)(v & 0x1FFFFu);
    }
}

// ====== gather fp8 (v4 structure): 8-lane group per node, work-steal pool ======
// Input rows are 64 ch fp8 = 64 B; each lane loads uint2 (8 ch), f32-accumulates,
// output written as bf16 (128 B rows) for the MFMA consumers.
__global__ __launch_bounds__(256) void agg_fp8(
    const uint2* __restrict__ in8, uint4* __restrict__ out4,
    const int* __restrict__ rowptr, const int* __restrict__ esrc)
{
    __shared__ int pool;
    if (threadIdx.x == 0) pool = 0;
    __syncthreads();

    int sub = threadIdx.x & 7;
    int wl  = threadIdx.x & 63;
    int base = blockIdx.x * AGG_NPB;
    int nmax = min(AGG_NPB, N_NODES - base);

    for (;;) {
        int n = 0;
        if (sub == 0) n = atomicAdd(&pool, 1);
        n = __shfl(n, wl & 56, 64);    // broadcast from group leader
        if (n >= nmax) break;
        int node = base + n;

        float a[8] = {0, 0, 0, 0, 0, 0, 0, 0};
        accum8_fp8(a, in8[(size_t)node * 8 + sub]);   // self term

        int e = rowptr[node], end = rowptr[node + 1];
        for (; e + 8 <= end; e += 8) {
            int i0 = esrc[e],     i1 = esrc[e + 1], i2 = esrc[e + 2], i3 = esrc[e + 3];
            int i4 = esrc[e + 4], i5 = esrc[e + 5], i6 = esrc[e + 6], i7 = esrc[e + 7];
            uint2 v0 = in8[(size_t)i0 * 8 + sub];
            uint2 v1 = in8[(size_t)i1 * 8 + sub];
            uint2 v2 = in8[(size_t)i2 * 8 + sub];
            uint2 v3 = in8[(size_t)i3 * 8 + sub];
            uint2 v4 = in8[(size_t)i4 * 8 + sub];
            uint2 v5 = in8[(size_t)i5 * 8 + sub];
            uint2 v6 = in8[(size_t)i6 * 8 + sub];
            uint2 v7 = in8[(size_t)i7 * 8 + sub];
            accum8_fp8(a, v0); accum8_fp8(a, v1); accum8_fp8(a, v2); accum8_fp8(a, v3);
            accum8_fp8(a, v4); accum8_fp8(a, v5); accum8_fp8(a, v6); accum8_fp8(a, v7);
        }
        if (e + 4 <= end) {
            int i0 = esrc[e], i1 = esrc[e + 1], i2 = esrc[e + 2], i3 = esrc[e + 3];
            uint2 v0 = in8[(size_t)i0 * 8 + sub];
            uint2 v1 = in8[(size_t)i1 * 8 + sub];
            uint2 v2 = in8[(size_t)i2 * 8 + sub];
            uint2 v3 = in8[(size_t)i3 * 8 + sub];
            accum8_fp8(a, v0); accum8_fp8(a, v1); accum8_fp8(a, v2); accum8_fp8(a, v3);
            e += 4;
        }
        for (; e < end; ++e)
            accum8_fp8(a, in8[(size_t)esrc[e] * 8 + sub]);

        uint4 o;
        o.x = (uint)f2bf(a[0]) | ((uint)f2bf(a[1]) << 16);
        o.y = (uint)f2bf(a[2]) | ((uint)f2bf(a[3]) << 16);
        o.z = (uint)f2bf(a[4]) | ((uint)f2bf(a[5]) << 16);
        o.w = (uint)f2bf(a[6]) | ((uint)f2bf(a[7]) << 16);
        out4[(size_t)node * 8 + sub] = o;
    }
}

// ===== fused_mid: t=relu(yagg+b1); h1=relu(t@W2+b2); z=h1@W3 (bf16 MFMA, fp8 out) =====
__global__ __launch_bounds__(256) void fused_mid(
    const ushort* __restrict__ yagg, const float* __restrict__ b1,
    const float* __restrict__ W2, const float* __restrict__ b2,
    const float* __restrict__ W3, unsigned char* __restrict__ z8)
{
    __shared__ __align__(16) float trs[4][16 * 68];
    int lane = threadIdx.x & 63, wave = threadIdx.x >> 6;
    int lg = lane >> 4, lm = lane & 15;

    bf16x8 B2[2][4], B3[2][4];
    #pragma unroll
    for (int kc = 0; kc < 2; ++kc)
        #pragma unroll
        for (int cb = 0; cb < 4; ++cb) {
            bf16x8 t2, t3;
            #pragma unroll
            for (int i = 0; i < 8; ++i) {
                int k = kc * 32 + lg * 8 + i;
                int cc = cb * 16 + lm;
                t2[i] = (short)f2bf(W2[k * 64 + cc]);
                t3[i] = (short)f2bf(W3[k * 64 + cc]);
            }
            B2[kc][cb] = t2; B3[kc][cb] = t3;
        }
    float b1r[2][8];
    #pragma unroll
    for (int kc = 0; kc < 2; ++kc)
        #pragma unroll
        for (int i = 0; i < 8; ++i)
            b1r[kc][i] = b1[kc * 32 + lg * 8 + i];
    float b2r[4];
    #pragma unroll
    for (int cb = 0; cb < 4; ++cb) b2r[cb] = b2[cb * 16 + lm];

    const int ntiles = N_NODES / 16;
    for (int tile = blockIdx.x * 4 + wave; tile < ntiles; tile += GEMM_GS * 4) {
        int r = tile * 16 + lm;
        bf16x8 A1[2];
        #pragma unroll
        for (int kc = 0; kc < 2; ++kc) {
            uint4 raw = *(const uint4*)(yagg + (size_t)r * 64 + kc * 32 + lg * 8);
            uint w[4] = {raw.x, raw.y, raw.z, raw.w};
            bf16x8 t;
            #pragma unroll
            for (int j = 0; j < 4; ++j) {
                float flo = bf2f((ushort)(w[j] & 0xffffu)) + b1r[kc][2 * j];
                float fhi = bf2f((ushort)(w[j] >> 16)) + b1r[kc][2 * j + 1];
                t[2 * j]     = (short)f2bf(fmaxf(flo, 0.0f));
                t[2 * j + 1] = (short)f2bf(fmaxf(fhi, 0.0f));
            }
            A1[kc] = t;
        }
        f32x4 acc[4] = {};
        #pragma unroll
        for (int kc = 0; kc < 2; ++kc)
            #pragma unroll
            for (int cb = 0; cb < 4; ++cb)
                acc[cb] = __builtin_amdgcn_mfma_f32_16x16x32_bf16(A1[kc], B2[kc][cb], acc[cb], 0, 0, 0);
        #pragma unroll
        for (int cb = 0; cb < 4; ++cb)
            #pragma unroll
            for (int i = 0; i < 4; ++i)
                trs[wave][(lg * 4 + i) * 68 + cb * 16 + lm] = fmaxf(acc[cb][i] + b2r[cb], 0.0f);
        bf16x8 A2[2];
        #pragma unroll
        for (int kc = 0; kc < 2; ++kc) {
            const float* p = &trs[wave][lm * 68 + kc * 32 + lg * 8];
            float4 u0 = *(const float4*)p;
            float4 u1 = *(const float4*)(p + 4);
            bf16x8 t;
            t[0] = (short)f2bf(u0.x); t[1] = (short)f2bf(u0.y);
            t[2] = (short)f2bf(u0.z); t[3] = (short)f2bf(u0.w);
            t[4] = (short)f2bf(u1.x); t[5] = (short)f2bf(u1.y);
            t[6] = (short)f2bf(u1.z); t[7] = (short)f2bf(u1.w);
            A2[kc] = t;
        }
        f32x4 acc2[4] = {};
        #pragma unroll
        for (int kc = 0; kc < 2; ++kc)
            #pragma unroll
            for (int cb = 0; cb < 4; ++cb)
                acc2[cb] = __builtin_amdgcn_mfma_f32_16x16x32_bf16(A2[kc], B3[kc][cb], acc2[cb], 0, 0, 0);
        #pragma unroll
        for (int cb = 0; cb < 4; ++cb)
            #pragma unroll
            for (int i = 0; i < 4; ++i)
                z8[(size_t)(tile * 16 + lg * 4 + i) * 64 + cb * 16 + lm] = f2fp8(acc2[cb][i]);
    }
}

// ===== k4 MFMA: o = relu(zagg+b3)@W4+b4 ; pooled[batch[r]] += o =====
__global__ __launch_bounds__(256) void k4_mfma_pool(
    const ushort* __restrict__ zagg, const float* __restrict__ b3,
    const float* __restrict__ W4, const float* __restrict__ b4,
    const int* __restrict__ batch, float* __restrict__ pooled)
{
    int lane = threadIdx.x & 63, wave = threadIdx.x >> 6;
    int lg = lane >> 4, lm = lane & 15;

    bf16x8 B4[2][8];
    #pragma unroll
    for (int kc = 0; kc < 2; ++kc)
        #pragma unroll
        for (int cb = 0; cb < 8; ++cb) {
            bf16x8 t;
            #pragma unroll
            for (int i = 0; i < 8; ++i)
                t[i] = (short)f2bf(W4[(kc * 32 + lg * 8 + i) * 128 + cb * 16 + lm]);
            B4[kc][cb] = t;
        }
    float b3r[2][8];
    #pragma unroll
    for (int kc = 0; kc < 2; ++kc)
        #pragma unroll
        for (int i = 0; i < 8; ++i)
            b3r[kc][i] = b3[kc * 32 + lg * 8 + i];
    float b4r[8];
    #pragma unroll
    for (int cb = 0; cb < 8; ++cb) b4r[cb] = b4[cb * 16 + lm];

    const int NT = N_NODES / 16;   // 6250
    const int TPW = 4;
    int w = blockIdx.x * 4 + wave;
    int t0 = w * TPW;
    if (t0 >= NT) return;
    int t1 = min(t0 + TPW, NT);

    float pacc[8] = {0, 0, 0, 0, 0, 0, 0, 0};
    int curg = batch[t0 * 16];

#define FLUSH(G) do {                                                     \
        _Pragma("unroll")                                                 \
        for (int cb = 0; cb < 8; ++cb) {                                  \
            float v = pacc[cb];                                           \
            v += __shfl_xor(v, 16, 64);                                   \
            v += __shfl_xor(v, 32, 64);                                   \
            if (lane < 16) unsafeAtomicAdd(&pooled[(G) * 128 + cb * 16 + lm], v); \
            pacc[cb] = 0.0f;                                              \
        }                                                                 \
    } while (0)

    for (int t = t0; t < t1; ++t) {
        int rbase = t * 16;
        int r = rbase + lm;
        bf16x8 A[2];
        #pragma unroll
        for (int kc = 0; kc < 2; ++kc) {
            uint4 raw = *(const uint4*)(zagg + (size_t)r * 64 + kc * 32 + lg * 8);
            uint wv[4] = {raw.x, raw.y, raw.z, raw.w};
            bf16x8 tt;
            #pragma unroll
            for (int j = 0; j < 4; ++j) {
                float flo = bf2f((ushort)(wv[j] & 0xffffu)) + b3r[kc][2 * j];
                float fhi = bf2f((ushort)(wv[j] >> 16))    + b3r[kc][2 * j + 1];
                tt[2 * j]     = (short)f2bf(fmaxf(flo, 0.0f));
                tt[2 * j + 1] = (short)f2bf(fmaxf(fhi, 0.0f));
            }
            A[kc] = tt;
        }
        f32x4 acc[8] = {};
        #pragma unroll
        for (int kc = 0; kc < 2; ++kc)
            #pragma unroll
            for (int cb = 0; cb < 8; ++cb)
                acc[cb] = __builtin_amdgcn_mfma_f32_16x16x32_bf16(A[kc], B4[kc][cb], acc[cb], 0, 0, 0);

        int g0 = batch[rbase], g15 = batch[rbase + 15];
        if (g0 != curg) { FLUSH(curg); curg = g0; }
        if (g0 == g15) {
            #pragma unroll
            for (int cb = 0; cb < 8; ++cb)
                pacc[cb] += acc[cb][0] + acc[cb][1] + acc[cb][2] + acc[cb][3]
                            + 4.0f * b4r[cb];
        } else {
            FLUSH(curg);
            #pragma unroll
            for (int i = 0; i < 4; ++i) {
                int gi = batch[rbase + lg * 4 + i];
                #pragma unroll
                for (int cb = 0; cb < 8; ++cb)
                    unsafeAtomicAdd(&pooled[gi * 128 + cb * 16 + lm],
                                    acc[cb][i] + b4r[cb]);
            }
            curg = g15;
        }
    }
    FLUSH(curg);
#undef FLUSH
}

// ================= head =================
__global__ void head_kernel(
    const float* __restrict__ pooled, const int* __restrict__ batch,
    const float* __restrict__ Wfc, const float* __restrict__ bfc,
    float* __restrict__ out)
{
    int g = threadIdx.x;
    if (g >= NUM_GRAPHS) return;

    int lo = 0, hi = N_NODES;
    while (lo < hi) { int mid = (lo + hi) >> 1; if (batch[mid] < g) lo = mid + 1; else hi = mid; }
    int beg = lo;
    lo = 0; hi = N_NODES;
    while (lo < hi) { int mid = (lo + hi) >> 1; if (batch[mid] < g + 1) lo = mid + 1; else hi = mid; }
    int cnt = lo - beg;
    float inv = 1.0f / fmaxf((float)cnt, 1.0f);

    float logits[10];
    for (int o = 0; o < 10; ++o) {
        float acc = 0.0f;
        for (int k = 0; k < 128; ++k)
            acc = fmaf(pooled[g * 128 + k], Wfc[k * 10 + o], acc);
        logits[o] = acc * inv + bfc[o];
    }
    float m = -INFINITY;
    for (int o = 0; o < 10; ++o) m = fmaxf(m, logits[o]);
    float s = 0.0f;
    for (int o = 0; o < 10; ++o) s += expf(logits[o] - m);
    float ls = logf(s);
    for (int o = 0; o < 10; ++o) out[g * 10 + o] = logits[o] - m - ls;
}

extern "C" void kernel_launch(void* const* d_in, const int* in_sizes, int n_in,
                              void* d_out, int out_size, void* d_ws, size_t ws_size,
                              hipStream_t stream)
{
    const float* x     = (const float*)d_in[0];
    const int*   ei    = (const int*)d_in[1];
    const int*   src   = ei;
    const int*   dst   = ei + N_EDGES;
    const int*   batch = (const int*)d_in[2];
    const float* W1  = (const float*)d_in[3];
    const float* b1  = (const float*)d_in[4];
    const float* W2  = (const float*)d_in[5];
    const float* b2  = (const float*)d_in[6];
    const float* W3  = (const float*)d_in[7];
    const float* b3  = (const float*)d_in[8];
    const float* W4  = (const float*)d_in[9];
    const float* b4  = (const float*)d_in[10];
    const float* Wfc = (const float*)d_in[11];
    const float* bfc = (const float*)d_in[12];
    float* out = (float*)d_out;

    char* ws = (char*)d_ws;
    unsigned char* yfp8 = (unsigned char*)(ws);              // 6.4 MB (fp8 y, pre-act)
    unsigned char* zfp8 = (unsigned char*)(ws + 6400000);    // 6.4 MB (fp8 z, pre-act)
    ushort* yagg  = (ushort*)(ws + 12800000);                // 12.8 MB (bf16)
    ushort* zagg  = (ushort*)(ws + 25600000);                // 12.8 MB (bf16)
    int*  esrc    = (int*) (ws + 38400000);                  // 6.4 MB
    uint* epack   = (uint*)(ws + 44800000);                  // 6.4 MB
    int*  rowptr  = (int*) (ws + 51200000);                  // 400,004 B
    int*  bcount  = (int*) (ws + 51600016);                  // 613,088 B
    int*  basetab = (int*) (ws + 52213104);                  // 613,088 B
    int*  btot    = (int*) (ws + 52826192);                  // 784 B
    int*  gbase   = (int*) (ws + 52826976);                  // 788 B
    float* pooled = (float*)(ws + 52827776);                 // 32 KB

    // ---- K1: coarse hist + gemm1 (fp8 out) ----
    k1_hist_gemm<<<NB1 + GEMM_GS, 256, 0, stream>>>(dst, bcount, x, W1, yfp8);
    // ---- CSR build ----
    p2a_scan<<<NBUCK, 256, 0, stream>>>(bcount, basetab, btot);
    p2b_scan<<<1, 256, 0, stream>>>(btot, gbase, pooled);
    p3_partition<<<NB1, 256, 0, stream>>>(src, dst, basetab, gbase, epack);
    p4_fine<<<NBUCK, 256, 0, stream>>>(epack, gbase, rowptr, esrc);

    // ---- layer 1 ----
    agg_fp8<<<(N_NODES + AGG_NPB - 1) / AGG_NPB, 256, 0, stream>>>(
        (const uint2*)yfp8, (uint4*)yagg, rowptr, esrc);
    fused_mid<<<GEMM_GS, 256, 0, stream>>>(yagg, b1, W2, b2, W3, zfp8);

    // ---- layer 2 ----
    agg_fp8<<<(N_NODES + AGG_NPB - 1) / AGG_NPB, 256, 0, stream>>>(
        (const uint2*)zfp8, (uint4*)zagg, rowptr, esrc);
    {
        const int NT = N_NODES / 16;   // 6250
        const int TPW = 4;
        int blocks = (NT + 4 * TPW - 1) / (4 * TPW);   // 391
        k4_mfma_pool<<<blocks, 256, 0, stream>>>(zagg, b3, W4, b4, batch, pooled);
    }

    head_kernel<<<1, 64, 0, stream>>>(pooled, batch, Wfc, bfc, out);
}

// Round 18
// 168.796 us; speedup vs baseline: 1.0783x; 1.0034x over previous
//
#include <hip/hip_runtime.h>
#include <cmath>

#define N_NODES    100000
#define N_EDGES    1600000
#define NUM_GRAPHS 64

// counting-sort geometry
#define BUCK_W     512                               // nodes per coarse bucket
#define NBUCK      196                               // ceil(100000/512)
#define EPB        2048                              // edges per partition block
#define NB1        782                               // ceil(1600000/2048)
#define GEMM_GS    782                               // grid-stride blocks for gemm1/fused_mid
#define AGG_NPB    32                                // nodes per agg block (3125 blocks)

typedef __attribute__((ext_vector_type(8))) short bf16x8;
typedef __attribute__((ext_vector_type(4))) float f32x4;
typedef __attribute__((ext_vector_type(2))) float f32x2;

// f32 -> bf16 RTNE via native __bf16 cast (compiler emits v_cvt_pk_bf16_f32)
__device__ __forceinline__ ushort f2bf(float x) {
    __bf16 b = (__bf16)x;
    return __builtin_bit_cast(ushort, b);
}
__device__ __forceinline__ float bf2f(ushort u) {
    union { uint u; float f; } v; v.u = ((uint)u) << 16;
    return v.f;
}
// f32 -> fp8 e4m3 (OCP) via HW converter, low byte
__device__ __forceinline__ unsigned char f2fp8(float v) {
    int p = __builtin_amdgcn_cvt_pk_fp8_f32(v, v, 0, false);
    return (unsigned char)(p & 0xFF);
}
// accumulate 8 fp8 channels (one uint2) into f32 accumulators
__device__ __forceinline__ void accum8_fp8(float* a, uint2 V) {
    f32x2 d0 = __builtin_amdgcn_cvt_pk_f32_fp8((int)V.x, false);
    f32x2 d1 = __builtin_amdgcn_cvt_pk_f32_fp8((int)V.x, true);
    f32x2 d2 = __builtin_amdgcn_cvt_pk_f32_fp8((int)V.y, false);
    f32x2 d3 = __builtin_amdgcn_cvt_pk_f32_fp8((int)V.y, true);
    a[0] += d0.x; a[1] += d0.y; a[2] += d1.x; a[3] += d1.y;
    a[4] += d2.x; a[5] += d2.y; a[6] += d3.x; a[7] += d3.y;
}

// ========== K1: coarse histogram (blocks [0,NB1)) + gemm1 grid-stride (rest) ==========
// gemm1 emits y in fp8 e4m3 (the gathered representation, pre-activation).
__global__ __launch_bounds__(256) void k1_hist_gemm(
    const int* __restrict__ dst, int* __restrict__ bcount,
    const float* __restrict__ x, const float* __restrict__ W1,
    unsigned char* __restrict__ y8)
{
    if (blockIdx.x < NB1) {
        __shared__ int shist[NBUCK];
        int tid = threadIdx.x;
        for (int i = tid; i < NBUCK; i += 256) shist[i] = 0;
        __syncthreads();
        int e0 = blockIdx.x * EPB + tid;
        #pragma unroll
        for (int k = 0; k < EPB / 256; ++k) {
            int e = e0 + k * 256;
            if (e < N_EDGES) atomicAdd(&shist[dst[e] >> 9], 1);
        }
        __syncthreads();
        for (int i = tid; i < NBUCK; i += 256)
            bcount[blockIdx.x * NBUCK + i] = shist[i];
        return;
    }
    int bid = blockIdx.x - NB1;
    int lane = threadIdx.x & 63, wave = threadIdx.x >> 6;
    int lg = lane >> 4, lm = lane & 15;

    bf16x8 Bf[4][4];
    #pragma unroll
    for (int kc = 0; kc < 4; ++kc)
        #pragma unroll
        for (int cb = 0; cb < 4; ++cb) {
            bf16x8 t;
            #pragma unroll
            for (int i = 0; i < 8; ++i)
                t[i] = (short)f2bf(W1[(kc * 32 + lg * 8 + i) * 64 + cb * 16 + lm]);
            Bf[kc][cb] = t;
        }

    const int ntiles = N_NODES / 16;   // 6250
    for (int tile = bid * 4 + wave; tile < ntiles; tile += GEMM_GS * 4) {
        int r = tile * 16 + lm;
        f32x4 acc[4] = {};
        #pragma unroll
        for (int kc = 0; kc < 4; ++kc) {
            const float* p = x + (size_t)r * 128 + kc * 32 + lg * 8;
            float4 a0 = *(const float4*)p;
            float4 a1 = *(const float4*)(p + 4);
            bf16x8 af;
            af[0] = (short)f2bf(a0.x); af[1] = (short)f2bf(a0.y);
            af[2] = (short)f2bf(a0.z); af[3] = (short)f2bf(a0.w);
            af[4] = (short)f2bf(a1.x); af[5] = (short)f2bf(a1.y);
            af[6] = (short)f2bf(a1.z); af[7] = (short)f2bf(a1.w);
            #pragma unroll
            for (int cb = 0; cb < 4; ++cb)
                acc[cb] = __builtin_amdgcn_mfma_f32_16x16x32_bf16(af, Bf[kc][cb], acc[cb], 0, 0, 0);
        }
        #pragma unroll
        for (int cb = 0; cb < 4; ++cb)
            #pragma unroll
            for (int i = 0; i < 4; ++i)
                y8[(size_t)(tile * 16 + lg * 4 + i) * 64 + cb * 16 + lm] = f2fp8(acc[cb][i]);
    }
}

// ========== P2a: per-bucket exclusive scan over NB1 block counts (parallel) ==========
#define SCH 4   // 256*4 = 1024 >= NB1
__global__ __launch_bounds__(256) void p2a_scan(
    const int* __restrict__ bcount, int* __restrict__ basetab,
    int* __restrict__ btot)
{
    __shared__ int sh[256];
    int b = blockIdx.x, tid = threadIdx.x;
    int v[SCH];
    int tsum = 0;
    #pragma unroll
    for (int j = 0; j < SCH; ++j) {
        int blk = tid * SCH + j;
        v[j] = (blk < NB1) ? bcount[(size_t)blk * NBUCK + b] : 0;
        tsum += v[j];
    }
    sh[tid] = tsum;
    __syncthreads();
    for (int off = 1; off < 256; off <<= 1) {
        int t = (tid >= off) ? sh[tid - off] : 0;
        __syncthreads();
        sh[tid] += t;
        __syncthreads();
    }
    if (tid == 255) btot[b] = sh[255];
    int excl = sh[tid] - tsum;
    #pragma unroll
    for (int j = 0; j < SCH; ++j) {
        int blk = tid * SCH + j;
        if (blk < NB1) basetab[(size_t)b * NB1 + blk] = excl;
        excl += v[j];
    }
}

// ========== P2b: exclusive scan of bucket totals -> gbase ; zero pooled ==========
__global__ __launch_bounds__(256) void p2b_scan(
    const int* __restrict__ btot, int* __restrict__ gbase,
    float* __restrict__ pooled)
{
    int tid = threadIdx.x;
    for (int i = tid; i < NUM_GRAPHS * 128; i += 256) pooled[i] = 0.0f;
    __shared__ int v[NBUCK];
    for (int j = tid; j < NBUCK; j += 256) v[j] = btot[j];
    __syncthreads();
    if (tid == 0) {
        int run = 0;
        for (int j = 0; j < NBUCK; ++j) { int t = v[j]; v[j] = run; run += t; }
        gbase[NBUCK] = run;   // == N_EDGES
    }
    __syncthreads();
    for (int j = tid; j < NBUCK; j += 256) gbase[j] = v[j];
}

// ========== P3 v2: LDS counting-sort, then bucket-ordered COALESCED writes ==========
// global addr of LDS-ordered index j = sbase[bin(j)] + j  (affine in j within segment)
__global__ __launch_bounds__(256) void p3_partition(
    const int* __restrict__ src, const int* __restrict__ dst,
    const int* __restrict__ basetab, const int* __restrict__ gbase,
    uint* __restrict__ epack)
{
    __shared__ int shist[NBUCK];          // hist -> exclusive seg starts
    __shared__ int scur[NBUCK];           // scatter cursors
    __shared__ int sbase[NBUCK];          // global base - LDS seg start
    __shared__ uint lbuf[EPB];            // 8 KB packed edges, bucket-sorted
    __shared__ unsigned char lbin[EPB];   // 2 KB bucket id per slot

    int blk = blockIdx.x, tid = threadIdx.x;
    int cnt = min(EPB, N_EDGES - blk * EPB);

    for (int i = tid; i < NBUCK; i += 256) shist[i] = 0;
    __syncthreads();

    uint mypack[EPB / 256];
    int  mybin[EPB / 256];
    #pragma unroll
    for (int k = 0; k < EPB / 256; ++k) {
        int e = blk * EPB + tid + k * 256;
        if (e < N_EDGES) {
            int d = dst[e], s = src[e];
            mybin[k] = d >> 9;
            mypack[k] = ((uint)(d & 511) << 17) | (uint)s;
            atomicAdd(&shist[mybin[k]], 1);
        } else mybin[k] = -1;
    }
    __syncthreads();
    if (tid == 0) {
        int run = 0;
        for (int i = 0; i < NBUCK; ++i) { int t = shist[i]; shist[i] = run; run += t; }
    }
    __syncthreads();
    for (int i = tid; i < NBUCK; i += 256) {
        scur[i] = shist[i];
        sbase[i] = basetab[(size_t)i * NB1 + blk] + gbase[i] - shist[i];
    }
    __syncthreads();
    #pragma unroll
    for (int k = 0; k < EPB / 256; ++k) {
        if (mybin[k] >= 0) {
            int p = atomicAdd(&scur[mybin[k]], 1);
            lbuf[p] = mypack[k];
            lbin[p] = (unsigned char)mybin[k];
        }
    }
    __syncthreads();
    for (int j = tid; j < cnt; j += 256) {
        int bin = lbin[j];
        epack[sbase[bin] + j] = lbuf[j];
    }
}

// ========== P4: per-bucket fine CSR (rowptr + esrc), all LDS ==========
__global__ __launch_bounds__(256) void p4_fine(
    const uint* __restrict__ epack, const int* __restrict__ gbase,
    int* __restrict__ rowptr, int* __restrict__ esrc)
{
    __shared__ int hist[BUCK_W];
    int b = blockIdx.x, tid = threadIdx.x;
    int beg = gbase[b], end = gbase[b + 1];
    for (int i = tid; i < BUCK_W; i += 256) hist[i] = 0;
    __syncthreads();
    for (int e = beg + tid; e < end; e += 256)
        atomicAdd(&hist[epack[e] >> 17], 1);
    __syncthreads();
    if (tid == 0) {
        int run = 0;
        for (int i = 0; i < BUCK_W; ++i) { int t = hist[i]; hist[i] = run; run += t; }
    }
    __syncthreads();
    for (int i = tid; i < BUCK_W; i += 256) {
        int n = b * BUCK_W + i;
        if (n < N_NODES) rowptr[n] = beg + hist[i];
    }
    if (b == NBUCK - 1 && tid == 0) rowptr[N_NODES] = end;
    __syncthreads();
    for (int e = beg + tid; e < end; e += 256) {
        uint v = epack[e];
        int slot = beg + atomicAdd(&hist[v >> 17], 1);
        esrc[slot] = (int)(v & 0x1FFFFu);
    }
}

// ====== gather fp8 (v4 structure): 8-lane group per node, work-steal pool ======
// Input rows are 64 ch fp8 = 64 B; each lane loads uint2 (8 ch), f32-accumulates,
// output written as bf16 (128 B rows) for the MFMA consumers.
__global__ __launch_bounds__(256) void agg_fp8(
    const uint2* __restrict__ in8, uint4* __restrict__ out4,
    const int* __restrict__ rowptr, const int* __restrict__ esrc)
{
    __shared__ int pool;
    if (threadIdx.x == 0) pool = 0;
    __syncthreads();

    int sub = threadIdx.x & 7;
    int wl  = threadIdx.x & 63;
    int base = blockIdx.x * AGG_NPB;
    int nmax = min(AGG_NPB, N_NODES - base);

    for (;;) {
        int n = 0;
        if (sub == 0) n = atomicAdd(&pool, 1);
        n = __shfl(n, wl & 56, 64);    // broadcast from group leader
        if (n >= nmax) break;
        int node = base + n;

        float a[8] = {0, 0, 0, 0, 0, 0, 0, 0};
        accum8_fp8(a, in8[(size_t)node * 8 + sub]);   // self term

        int e = rowptr[node], end = rowptr[node + 1];
        for (; e + 8 <= end; e += 8) {
            int i0 = esrc[e],     i1 = esrc[e + 1], i2 = esrc[e + 2], i3 = esrc[e + 3];
            int i4 = esrc[e + 4], i5 = esrc[e + 5], i6 = esrc[e + 6], i7 = esrc[e + 7];
            uint2 v0 = in8[(size_t)i0 * 8 + sub];
            uint2 v1 = in8[(size_t)i1 * 8 + sub];
            uint2 v2 = in8[(size_t)i2 * 8 + sub];
            uint2 v3 = in8[(size_t)i3 * 8 + sub];
            uint2 v4 = in8[(size_t)i4 * 8 + sub];
            uint2 v5 = in8[(size_t)i5 * 8 + sub];
            uint2 v6 = in8[(size_t)i6 * 8 + sub];
            uint2 v7 = in8[(size_t)i7 * 8 + sub];
            accum8_fp8(a, v0); accum8_fp8(a, v1); accum8_fp8(a, v2); accum8_fp8(a, v3);
            accum8_fp8(a, v4); accum8_fp8(a, v5); accum8_fp8(a, v6); accum8_fp8(a, v7);
        }
        if (e + 4 <= end) {
            int i0 = esrc[e], i1 = esrc[e + 1], i2 = esrc[e + 2], i3 = esrc[e + 3];
            uint2 v0 = in8[(size_t)i0 * 8 + sub];
            uint2 v1 = in8[(size_t)i1 * 8 + sub];
            uint2 v2 = in8[(size_t)i2 * 8 + sub];
            uint2 v3 = in8[(size_t)i3 * 8 + sub];
            accum8_fp8(a, v0); accum8_fp8(a, v1); accum8_fp8(a, v2); accum8_fp8(a, v3);
            e += 4;
        }
        for (; e < end; ++e)
            accum8_fp8(a, in8[(size_t)esrc[e] * 8 + sub]);

        uint4 o;
        o.x = (uint)f2bf(a[0]) | ((uint)f2bf(a[1]) << 16);
        o.y = (uint)f2bf(a[2]) | ((uint)f2bf(a[3]) << 16);
        o.z = (uint)f2bf(a[4]) | ((uint)f2bf(a[5]) << 16);
        o.w = (uint)f2bf(a[6]) | ((uint)f2bf(a[7]) << 16);
        out4[(size_t)node * 8 + sub] = o;
    }
}

// ===== fused_mid: t=relu(yagg+b1); h1=relu(t@W2+b2); z=h1@W3 (bf16 MFMA, fp8 out) =====
__global__ __launch_bounds__(256) void fused_mid(
    const ushort* __restrict__ yagg, const float* __restrict__ b1,
    const float* __restrict__ W2, const float* __restrict__ b2,
    const float* __restrict__ W3, unsigned char* __restrict__ z8)
{
    __shared__ __align__(16) float trs[4][16 * 68];
    int lane = threadIdx.x & 63, wave = threadIdx.x >> 6;
    int lg = lane >> 4, lm = lane & 15;

    bf16x8 B2[2][4], B3[2][4];
    #pragma unroll
    for (int kc = 0; kc < 2; ++kc)
        #pragma unroll
        for (int cb = 0; cb < 4; ++cb) {
            bf16x8 t2, t3;
            #pragma unroll
            for (int i = 0; i < 8; ++i) {
                int k = kc * 32 + lg * 8 + i;
                int cc = cb * 16 + lm;
                t2[i] = (short)f2bf(W2[k * 64 + cc]);
                t3[i] = (short)f2bf(W3[k * 64 + cc]);
            }
            B2[kc][cb] = t2; B3[kc][cb] = t3;
        }
    float b1r[2][8];
    #pragma unroll
    for (int kc = 0; kc < 2; ++kc)
        #pragma unroll
        for (int i = 0; i < 8; ++i)
            b1r[kc][i] = b1[kc * 32 + lg * 8 + i];
    float b2r[4];
    #pragma unroll
    for (int cb = 0; cb < 4; ++cb) b2r[cb] = b2[cb * 16 + lm];

    const int ntiles = N_NODES / 16;
    for (int tile = blockIdx.x * 4 + wave; tile < ntiles; tile += GEMM_GS * 4) {
        int r = tile * 16 + lm;
        bf16x8 A1[2];
        #pragma unroll
        for (int kc = 0; kc < 2; ++kc) {
            uint4 raw = *(const uint4*)(yagg + (size_t)r * 64 + kc * 32 + lg * 8);
            uint w[4] = {raw.x, raw.y, raw.z, raw.w};
            bf16x8 t;
            #pragma unroll
            for (int j = 0; j < 4; ++j) {
                float flo = bf2f((ushort)(w[j] & 0xffffu)) + b1r[kc][2 * j];
                float fhi = bf2f((ushort)(w[j] >> 16)) + b1r[kc][2 * j + 1];
                t[2 * j]     = (short)f2bf(fmaxf(flo, 0.0f));
                t[2 * j + 1] = (short)f2bf(fmaxf(fhi, 0.0f));
            }
            A1[kc] = t;
        }
        f32x4 acc[4] = {};
        #pragma unroll
        for (int kc = 0; kc < 2; ++kc)
            #pragma unroll
            for (int cb = 0; cb < 4; ++cb)
                acc[cb] = __builtin_amdgcn_mfma_f32_16x16x32_bf16(A1[kc], B2[kc][cb], acc[cb], 0, 0, 0);
        #pragma unroll
        for (int cb = 0; cb < 4; ++cb)
            #pragma unroll
            for (int i = 0; i < 4; ++i)
                trs[wave][(lg * 4 + i) * 68 + cb * 16 + lm] = fmaxf(acc[cb][i] + b2r[cb], 0.0f);
        bf16x8 A2[2];
        #pragma unroll
        for (int kc = 0; kc < 2; ++kc) {
            const float* p = &trs[wave][lm * 68 + kc * 32 + lg * 8];
            float4 u0 = *(const float4*)p;
            float4 u1 = *(const float4*)(p + 4);
            bf16x8 t;
            t[0] = (short)f2bf(u0.x); t[1] = (short)f2bf(u0.y);
            t[2] = (short)f2bf(u0.z); t[3] = (short)f2bf(u0.w);
            t[4] = (short)f2bf(u1.x); t[5] = (short)f2bf(u1.y);
            t[6] = (short)f2bf(u1.z); t[7] = (short)f2bf(u1.w);
            A2[kc] = t;
        }
        f32x4 acc2[4] = {};
        #pragma unroll
        for (int kc = 0; kc < 2; ++kc)
            #pragma unroll
            for (int cb = 0; cb < 4; ++cb)
                acc2[cb] = __builtin_amdgcn_mfma_f32_16x16x32_bf16(A2[kc], B3[kc][cb], acc2[cb], 0, 0, 0);
        #pragma unroll
        for (int cb = 0; cb < 4; ++cb)
            #pragma unroll
            for (int i = 0; i < 4; ++i)
                z8[(size_t)(tile * 16 + lg * 4 + i) * 64 + cb * 16 + lm] = f2fp8(acc2[cb][i]);
    }
}

// ===== k4 MFMA: o = relu(zagg+b3)@W4+b4 ; pooled[batch[r]] += o =====
__global__ __launch_bounds__(256) void k4_mfma_pool(
    const ushort* __restrict__ zagg, const float* __restrict__ b3,
    const float* __restrict__ W4, const float* __restrict__ b4,
    const int* __restrict__ batch, float* __restrict__ pooled)
{
    int lane = threadIdx.x & 63, wave = threadIdx.x >> 6;
    int lg = lane >> 4, lm = lane & 15;

    bf16x8 B4[2][8];
    #pragma unroll
    for (int kc = 0; kc < 2; ++kc)
        #pragma unroll
        for (int cb = 0; cb < 8; ++cb) {
            bf16x8 t;
            #pragma unroll
            for (int i = 0; i < 8; ++i)
                t[i] = (short)f2bf(W4[(kc * 32 + lg * 8 + i) * 128 + cb * 16 + lm]);
            B4[kc][cb] = t;
        }
    float b3r[2][8];
    #pragma unroll
    for (int kc = 0; kc < 2; ++kc)
        #pragma unroll
        for (int i = 0; i < 8; ++i)
            b3r[kc][i] = b3[kc * 32 + lg * 8 + i];
    float b4r[8];
    #pragma unroll
    for (int cb = 0; cb < 8; ++cb) b4r[cb] = b4[cb * 16 + lm];

    const int NT = N_NODES / 16;   // 6250
    const int TPW = 4;
    int w = blockIdx.x * 4 + wave;
    int t0 = w * TPW;
    if (t0 >= NT) return;
    int t1 = min(t0 + TPW, NT);

    float pacc[8] = {0, 0, 0, 0, 0, 0, 0, 0};
    int curg = batch[t0 * 16];

#define FLUSH(G) do {                                                     \
        _Pragma("unroll")                                                 \
        for (int cb = 0; cb < 8; ++cb) {                                  \
            float v = pacc[cb];                                           \
            v += __shfl_xor(v, 16, 64);                                   \
            v += __shfl_xor(v, 32, 64);                                   \
            if (lane < 16) unsafeAtomicAdd(&pooled[(G) * 128 + cb * 16 + lm], v); \
            pacc[cb] = 0.0f;                                              \
        }                                                                 \
    } while (0)

    for (int t = t0; t < t1; ++t) {
        int rbase = t * 16;
        int r = rbase + lm;
        bf16x8 A[2];
        #pragma unroll
        for (int kc = 0; kc < 2; ++kc) {
            uint4 raw = *(const uint4*)(zagg + (size_t)r * 64 + kc * 32 + lg * 8);
            uint wv[4] = {raw.x, raw.y, raw.z, raw.w};
            bf16x8 tt;
            #pragma unroll
            for (int j = 0; j < 4; ++j) {
                float flo = bf2f((ushort)(wv[j] & 0xffffu)) + b3r[kc][2 * j];
                float fhi = bf2f((ushort)(wv[j] >> 16))    + b3r[kc][2 * j + 1];
                tt[2 * j]     = (short)f2bf(fmaxf(flo, 0.0f));
                tt[2 * j + 1] = (short)f2bf(fmaxf(fhi, 0.0f));
            }
            A[kc] = tt;
        }
        f32x4 acc[8] = {};
        #pragma unroll
        for (int kc = 0; kc < 2; ++kc)
            #pragma unroll
            for (int cb = 0; cb < 8; ++cb)
                acc[cb] = __builtin_amdgcn_mfma_f32_16x16x32_bf16(A[kc], B4[kc][cb], acc[cb], 0, 0, 0);

        int g0 = batch[rbase], g15 = batch[rbase + 15];
        if (g0 != curg) { FLUSH(curg); curg = g0; }
        if (g0 == g15) {
            #pragma unroll
            for (int cb = 0; cb < 8; ++cb)
                pacc[cb] += acc[cb][0] + acc[cb][1] + acc[cb][2] + acc[cb][3]
                            + 4.0f * b4r[cb];
        } else {
            FLUSH(curg);
            #pragma unroll
            for (int i = 0; i < 4; ++i) {
                int gi = batch[rbase + lg * 4 + i];
                #pragma unroll
                for (int cb = 0; cb < 8; ++cb)
                    unsafeAtomicAdd(&pooled[gi * 128 + cb * 16 + lm],
                                    acc[cb][i] + b4r[cb]);
            }
            curg = g15;
        }
    }
    FLUSH(curg);
#undef FLUSH
}

// ================= head =================
__global__ void head_kernel(
    const float* __restrict__ pooled, const int* __restrict__ batch,
    const float* __restrict__ Wfc, const float* __restrict__ bfc,
    float* __restrict__ out)
{
    int g = threadIdx.x;
    if (g >= NUM_GRAPHS) return;

    int lo = 0, hi = N_NODES;
    while (lo < hi) { int mid = (lo + hi) >> 1; if (batch[mid] < g) lo = mid + 1; else hi = mid; }
    int beg = lo;
    lo = 0; hi = N_NODES;
    while (lo < hi) { int mid = (lo + hi) >> 1; if (batch[mid] < g + 1) lo = mid + 1; else hi = mid; }
    int cnt = lo - beg;
    float inv = 1.0f / fmaxf((float)cnt, 1.0f);

    float logits[10];
    for (int o = 0; o < 10; ++o) {
        float acc = 0.0f;
        for (int k = 0; k < 128; ++k)
            acc = fmaf(pooled[g * 128 + k], Wfc[k * 10 + o], acc);
        logits[o] = acc * inv + bfc[o];
    }
    float m = -INFINITY;
    for (int o = 0; o < 10; ++o) m = fmaxf(m, logits[o]);
    float s = 0.0f;
    for (int o = 0; o < 10; ++o) s += expf(logits[o] - m);
    float ls = logf(s);
    for (int o = 0; o < 10; ++o) out[g * 10 + o] = logits[o] - m - ls;
}

extern "C" void kernel_launch(void* const* d_in, const int* in_sizes, int n_in,
                              void* d_out, int out_size, void* d_ws, size_t ws_size,
                              hipStream_t stream)
{
    const float* x     = (const float*)d_in[0];
    const int*   ei    = (const int*)d_in[1];
    const int*   src   = ei;
    const int*   dst   = ei + N_EDGES;
    const int*   batch = (const int*)d_in[2];
    const float* W1  = (const float*)d_in[3];
    const float* b1  = (const float*)d_in[4];
    const float* W2  = (const float*)d_in[5];
    const float* b2  = (const float*)d_in[6];
    const float* W3  = (const float*)d_in[7];
    const float* b3  = (const float*)d_in[8];
    const float* W4  = (const float*)d_in[9];
    const float* b4  = (const float*)d_in[10];
    const float* Wfc = (const float*)d_in[11];
    const float* bfc = (const float*)d_in[12];
    float* out = (float*)d_out;

    char* ws = (char*)d_ws;
    unsigned char* yfp8 = (unsigned char*)(ws);              // 6.4 MB (fp8 y, pre-act)
    unsigned char* zfp8 = (unsigned char*)(ws + 6400000);    // 6.4 MB (fp8 z, pre-act)
    ushort* yagg  = (ushort*)(ws + 12800000);                // 12.8 MB (bf16)
    ushort* zagg  = (ushort*)(ws + 25600000);                // 12.8 MB (bf16)
    int*  esrc    = (int*) (ws + 38400000);                  // 6.4 MB
    uint* epack   = (uint*)(ws + 44800000);                  // 6.4 MB
    int*  rowptr  = (int*) (ws + 51200000);                  // 400,004 B
    int*  bcount  = (int*) (ws + 51600016);                  // 613,088 B
    int*  basetab = (int*) (ws + 52213104);                  // 613,088 B
    int*  btot    = (int*) (ws + 52826192);                  // 784 B
    int*  gbase   = (int*) (ws + 52826976);                  // 788 B
    float* pooled = (float*)(ws + 52827776);                 // 32 KB

    // ---- K1: coarse hist + gemm1 (fp8 out) ----
    k1_hist_gemm<<<NB1 + GEMM_GS, 256, 0, stream>>>(dst, bcount, x, W1, yfp8);
    // ---- CSR build ----
    p2a_scan<<<NBUCK, 256, 0, stream>>>(bcount, basetab, btot);
    p2b_scan<<<1, 256, 0, stream>>>(btot, gbase, pooled);
    p3_partition<<<NB1, 256, 0, stream>>>(src, dst, basetab, gbase, epack);
    p4_fine<<<NBUCK, 256, 0, stream>>>(epack, gbase, rowptr, esrc);

    // ---- layer 1 ----
    agg_fp8<<<(N_NODES + AGG_NPB - 1) / AGG_NPB, 256, 0, stream>>>(
        (const uint2*)yfp8, (uint4*)yagg, rowptr, esrc);
    fused_mid<<<GEMM_GS, 256, 0, stream>>>(yagg, b1, W2, b2, W3, zfp8);

    // ---- layer 2 ----
    agg_fp8<<<(N_NODES + AGG_NPB - 1) / AGG_NPB, 256, 0, stream>>>(
        (const uint2*)zfp8, (uint4*)zagg, rowptr, esrc);
    {
        const int NT = N_NODES / 16;   // 6250
        const int TPW = 4;
        int blocks = (NT + 4 * TPW - 1) / (4 * TPW);   // 391
        k4_mfma_pool<<<blocks, 256, 0, stream>>>(zagg, b3, W4, b4, batch, pooled);
    }

    head_kernel<<<1, 64, 0, stream>>>(pooled, batch, Wfc, bfc, out);
}